// Round 1
// baseline (7100.650 us; speedup 1.0000x reference)
//
#include <hip/hip_runtime.h>
#include <cstdint>
#include <cstddef>

// Problem constants
#define BB 32
#define LL 1024
#define DD 1536
#define SS 101
#define NEGV (-1e4f)
#define NINF (-1e30f)

// workspace layout (float offsets)
#define NPE   (1024*1536)
#define NX2   (32768*256)
#define NX3   (32768*64)
#define NG    (32768*512)
#define NF2   (32768*128)
#define NEM   (32768*101)

#define OFF_PE    0
#define OFF_X2    (OFF_PE + NPE)        // Y1 -> X2 (in-place LN) -> later Hcat
#define OFF_X3    (OFF_X2 + NX2)
#define OFF_GF    (OFF_X3 + NX3)
#define OFF_GB    (OFF_GF + NG)
#define OFF_F2    (OFF_GF)              // reuse GF after LSTM
#define OFF_EMIS  (OFF_GF + NF2)
#define OFF_ALPHA (OFF_EMIS + NEM)
#define OFF_LOGZ  (OFF_ALPHA + NEM)
#define OFF_WT_F  (OFF_GB + NG)
#define OFF_WT_B  (OFF_WT_F + 32768)
#define OFF_BS_F  (OFF_WT_B + 32768)
#define OFF_BS_B  (OFF_BS_F + 512)
#define OFF_W1R   (OFF_BS_B + 512)
#define OFF_W2R   (OFF_W1R + 49152)

// ---------------- prep: PE (transposed [k][l]), Wih^T, bias sums, conv weights rearranged t-major ----------------
__global__ __launch_bounds__(256)
void prep_k(const float* __restrict__ Wihf, const float* __restrict__ Wihb,
            const float* __restrict__ bihf, const float* __restrict__ bhhf,
            const float* __restrict__ bihb, const float* __restrict__ bhhb,
            const float* __restrict__ w1, const float* __restrict__ w2,
            float* __restrict__ ws)
{
  int idx = blockIdx.x * 256 + threadIdx.x;
  if (idx < NPE) {
    int k = idx >> 10, l = idx & 1023;
    int j2 = (k >> 1) * 2;
    float freq = expf((float)j2 * (-9.210340371976184f / 1536.f));
    float ang = (float)l * freq;
    ws[OFF_PE + idx] = (k & 1) ? cosf(ang) : sinf(ang);
    return;
  }
  idx -= NPE;
  if (idx < 32768) { int k = idx >> 9, n = idx & 511; ws[OFF_WT_F + idx] = Wihf[n*64 + k]; return; }
  idx -= 32768;
  if (idx < 32768) { int k = idx >> 9, n = idx & 511; ws[OFF_WT_B + idx] = Wihb[n*64 + k]; return; }
  idx -= 32768;
  if (idx < 512) { ws[OFF_BS_F + idx] = bihf[idx] + bhhf[idx]; return; }
  idx -= 512;
  if (idx < 512) { ws[OFF_BS_B + idx] = bihb[idx] + bhhb[idx]; return; }
  idx -= 512;
  if (idx < 49152) {  // w1r[(t*256+c)*64+f] = w1[f][c][t]
    int f = idx & 63, tc = idx >> 6;
    int t = tc >> 8, c = tc & 255;
    ws[OFF_W1R + idx] = w1[(f*256 + c)*3 + t];
    return;
  }
  idx -= 49152;
  if (idx < 163840) { // w2r[(t*256+c)*128+f] = w2[f][c][t]
    int f = idx & 127, tc = idx >> 7;
    int t = tc >> 8, c = tc & 255;
    ws[OFF_W2R + idx] = w2[(f*256 + c)*5 + t];
  }
}

// ---------------- generic fp32 tiled GEMM ----------------
// AMODE 0: A[m][k] = emb[b][k][l] + PE[k][l]  (m=b*1024+l)
// AMODE 1: A[m][k] = Ap[m*lda+k]
// AMODE 2: conv im2col, k = t*256+c, A[m][k] = Ap[(m+t-PADT)*lda+c] (0 at batch edges)
template<int BM, int BN, int AMODE, int PADT, bool RELU>
__global__ __launch_bounds__(256)
void gemm_tpl(const float* __restrict__ Ap, const float* __restrict__ Bp,
              const float* __restrict__ biasp, float* __restrict__ Cp,
              const float* __restrict__ PEp, const float* __restrict__ EMBp,
              int M, int N, int K, int lda)
{
  constexpr int BK = 16;
  __shared__ __align__(16) float As[BK][BM + 4];
  __shared__ __align__(16) float Bs[BK][BN];
  constexpr int TX = BN / 8, TY = BM / 8;
  const int tid = threadIdx.x;
  const int tx = tid % TX, ty = tid / TX;
  const int m0 = blockIdx.x * BM;
  const int n0 = blockIdx.y * BN;
  float acc[8][8];
  #pragma unroll
  for (int i = 0; i < 8; i++)
    #pragma unroll
    for (int j = 0; j < 8; j++) acc[i][j] = 0.f;

  for (int k0 = 0; k0 < K; k0 += BK) {
    if constexpr (AMODE == 0) {
      #pragma unroll
      for (int i = 0; i < (BK*BM)/256; ++i) {
        int e = tid + i*256;
        int ml = e % BM, kk = e / BM;
        int row = m0 + ml; int b = row >> 10; int l = row & 1023;
        int k = k0 + kk;
        As[kk][ml] = EMBp[((size_t)b*DD + k)*LL + l] + PEp[(size_t)k*LL + l];
      }
    } else {
      #pragma unroll
      for (int i = 0; i < (BK*BM)/256; ++i) {
        int e = tid + i*256;
        int kk = e % BK, ml = e / BK;
        int row = m0 + ml; int k = k0 + kk;
        float v;
        if constexpr (AMODE == 1) {
          v = Ap[(size_t)row*lda + k];
        } else {
          int c = k & 255, t = k >> 8;
          int l = row & 1023, sl = l + t - PADT;
          v = ((unsigned)sl < 1024u) ? Ap[(size_t)(row + t - PADT)*lda + c] : 0.f;
        }
        As[kk][ml] = v;
      }
    }
    #pragma unroll
    for (int i = 0; i < (BK*BN)/256; ++i) {
      int e = tid + i*256;
      int nl = e % BN, kk = e / BN;
      Bs[kk][nl] = Bp[(size_t)(k0+kk)*N + n0 + nl];
    }
    __syncthreads();
    #pragma unroll
    for (int k = 0; k < BK; ++k) {
      float4 a0 = *(const float4*)&As[k][ty*4];
      float4 a1 = *(const float4*)&As[k][BM/2 + ty*4];
      float4 b0 = *(const float4*)&Bs[k][tx*4];
      float4 b1 = *(const float4*)&Bs[k][BN/2 + tx*4];
      float av[8] = {a0.x,a0.y,a0.z,a0.w,a1.x,a1.y,a1.z,a1.w};
      float bv[8] = {b0.x,b0.y,b0.z,b0.w,b1.x,b1.y,b1.z,b1.w};
      #pragma unroll
      for (int i = 0; i < 8; i++)
        #pragma unroll
        for (int j = 0; j < 8; j++) acc[i][j] += av[i]*bv[j];
    }
    __syncthreads();
  }
  float4 bias0 = *(const float4*)&biasp[n0 + tx*4];
  float4 bias1 = *(const float4*)&biasp[n0 + BN/2 + tx*4];
  float bn[8] = {bias0.x,bias0.y,bias0.z,bias0.w,bias1.x,bias1.y,bias1.z,bias1.w};
  #pragma unroll
  for (int i = 0; i < 8; i++) {
    int r = m0 + ((i < 4) ? (ty*4 + i) : (BM/2 + ty*4 + i - 4));
    float o[8];
    #pragma unroll
    for (int j = 0; j < 8; j++) {
      float v = acc[i][j] + bn[j];
      o[j] = RELU ? fmaxf(v, 0.f) : v;
    }
    *(float4*)&Cp[(size_t)r*N + n0 + tx*4] = make_float4(o[0],o[1],o[2],o[3]);
    *(float4*)&Cp[(size_t)r*N + n0 + BN/2 + tx*4] = make_float4(o[4],o[5],o[6],o[7]);
  }
}

// ---------------- LayerNorm + ReLU (in-place, one wave per 256-wide row) ----------------
__global__ __launch_bounds__(256)
void ln_relu_k(float* __restrict__ X, const float* __restrict__ g, const float* __restrict__ bt)
{
  const int lane = threadIdx.x & 63, wv = threadIdx.x >> 6;
  const size_t row = (size_t)blockIdx.x * 4 + wv;
  float4 v = *(const float4*)&X[row*256 + lane*4];
  float s = v.x + v.y + v.z + v.w;
  float q = v.x*v.x + v.y*v.y + v.z*v.z + v.w*v.w;
  #pragma unroll
  for (int d = 1; d < 64; d <<= 1) { s += __shfl_xor(s, d); q += __shfl_xor(q, d); }
  float mean = s * (1.f/256.f);
  float var = q * (1.f/256.f) - mean*mean;
  float inv = 1.f / sqrtf(var + 1e-5f);
  float4 gg = *(const float4*)&g[lane*4];
  float4 bb = *(const float4*)&bt[lane*4];
  float4 o;
  o.x = fmaxf(0.f, (v.x-mean)*inv*gg.x + bb.x);
  o.y = fmaxf(0.f, (v.y-mean)*inv*gg.y + bb.y);
  o.z = fmaxf(0.f, (v.z-mean)*inv*gg.z + bb.z);
  o.w = fmaxf(0.f, (v.w-mean)*inv*gg.w + bb.w);
  *(float4*)&X[row*256 + lane*4] = o;
}

// ---------------- LSTM recurrence: one block per (batch, dir), Whh row in VGPRs ----------------
__global__ __launch_bounds__(512, 2)
void lstm_k(const float* __restrict__ GF, const float* __restrict__ GB,
            const float* __restrict__ WhhF, const float* __restrict__ WhhB,
            float* __restrict__ Hcat)
{
  const int dir = blockIdx.y;
  const int b = blockIdx.x;
  const int j = threadIdx.x;
  const float* G = dir ? GB : GF;
  const float* Whh = dir ? WhhB : WhhF;
  float w[128];
  #pragma unroll
  for (int i = 0; i < 32; ++i) {
    float4 t4 = *(const float4*)&Whh[(size_t)j*128 + i*4];
    w[4*i] = t4.x; w[4*i+1] = t4.y; w[4*i+2] = t4.z; w[4*i+3] = t4.w;
  }
  __shared__ __align__(16) float hs[128];
  __shared__ float gs[512];
  if (j < 128) hs[j] = 0.f;
  float c = 0.f;
  __syncthreads();
  for (int step = 0; step < LL; ++step) {
    const int l = dir ? (1023 - step) : step;
    float acc = G[((size_t)b*LL + l)*512 + j];
    #pragma unroll
    for (int k = 0; k < 128; k += 4) {
      float4 h4 = *(const float4*)&hs[k];
      acc += h4.x*w[k] + h4.y*w[k+1] + h4.z*w[k+2] + h4.w*w[k+3];
    }
    float gv;
    if (j < 256 || j >= 384) gv = 1.f / (1.f + expf(-acc));  // i, f, o gates
    else gv = tanhf(acc);                                     // g gate
    gs[j] = gv;
    __syncthreads();
    if (j < 128) {
      float ig = gs[j], fg = gs[128+j], g2 = gs[256+j], og = gs[384+j];
      c = fg*c + ig*g2;
      float hh = og * tanhf(c);
      hs[j] = hh;
      Hcat[((size_t)b*LL + l)*256 + (dir << 7) + j] = hh;
    }
    __syncthreads();
  }
}

// ---------------- emissions: wave per position ----------------
__device__ __forceinline__ float wave_sum_f(float v){
  #pragma unroll
  for (int d = 1; d < 64; d <<= 1) v += __shfl_xor(v, d);
  return v;
}
__device__ __forceinline__ float wave_max_f(float v){
  #pragma unroll
  for (int d = 1; d < 64; d <<= 1) v = fmaxf(v, __shfl_xor(v, d));
  return v;
}
__device__ __forceinline__ float lse2f(float x, float y){
  float mx = fmaxf(x, y), mn = fminf(x, y);
  return mx + log1pf(expf(mn - mx));
}

__global__ __launch_bounds__(256)
void emis_k(const float* __restrict__ F2, const float* __restrict__ W,
            const float* __restrict__ bias, float* __restrict__ EM)
{
  const int lane = threadIdx.x & 63;
  const size_t m = (size_t)blockIdx.x * 4 + (threadIdx.x >> 6);
  float f1 = F2[m*128 + lane], f2 = F2[m*128 + 64 + lane];
  float e0 = f1*W[lane*2]   + f2*W[(64+lane)*2];
  float e1 = f1*W[lane*2+1] + f2*W[(64+lane)*2+1];
  e0 = wave_sum_f(e0) + bias[0];
  e1 = wave_sum_f(e1) + bias[1];
  float* row = EM + m*SS;
  row[lane] = (lane == 0) ? e0 : e1;
  if (lane < 37) row[64 + lane] = e1;
}

// ---------------- CRF forward (alpha + logZ), one wave per batch ----------------
__global__ __launch_bounds__(64)
void crf_fwd_k(const float* __restrict__ EM, const float* __restrict__ T,
               const float* __restrict__ startv, const float* __restrict__ endv,
               float* __restrict__ AL, float* __restrict__ LOGZ)
{
  const int b = blockIdx.x, lane = threadIdx.x;
  const int s1 = lane, s2 = 64 + lane;
  const bool has2 = lane < 37;
  const float* E = EM + (size_t)b*LL*SS;
  float* A = AL + (size_t)b*LL*SS;
  float ta1, tb1 = 0.f, tc1 = NINF, ta2 = 0.f, tb2 = 0.f, tc2 = NINF;
  if (s1 == 0)      { ta1 = T[0]; tb1 = T[100*101 + 0]; }
  else if (s1 == 1) { ta1 = T[1]; tb1 = T[100*101 + 1]; }
  else ta1 = T[(s1-1)*101 + s1];
  if (s1 >= 4) tc1 = T[s1*101 + 100];
  if (has2) {
    if (s2 <= 98) ta2 = T[(s2-1)*101 + s2];
    else if (s2 == 99) { ta2 = T[98*101 + 99]; tb2 = T[99*101 + 99]; }
    if (s2 <= 99) tc2 = T[s2*101 + 100];
  }
  float a1 = startv[s1] + E[s1];
  float a2 = has2 ? (startv[s2] + E[s2]) : NINF;
  A[s1] = a1;
  if (has2) A[s2] = a2;
  for (int l = 1; l < LL; ++l) {
    const float* e = E + (size_t)l*SS;
    float v1 = (s1 >= 4) ? a1 + tc1 : NINF;
    float v2 = (has2 && s2 <= 99) ? a2 + tc2 : NINF;
    float M = wave_max_f(fmaxf(v1, v2));
    float P = wave_sum_f(expf(v1 - M) + expf(v2 - M));
    float lse100 = M + logf(P);
    float a1m1 = __shfl_up(a1, 1);
    float a2m1 = __shfl_up(a2, 1);
    float a1t  = __shfl(a1, 63);
    float a0s  = __shfl(a1, 0);
    float a100 = __shfl(a2, 36);
    float n1;
    if (s1 <= 1) n1 = lse2f(a0s + ta1, a100 + tb1);
    else n1 = a1m1 + ta1;
    float n2 = NINF;
    if (has2) {
      if (s2 == 64) n2 = a1t + ta2;
      else if (s2 <= 98) n2 = a2m1 + ta2;
      else if (s2 == 99) n2 = lse2f(a2m1 + ta2, a2 + tb2);
      else n2 = lse100;
    }
    a1 = n1 + e[s1];
    a2 = has2 ? (n2 + e[s2]) : NINF;
    float* Ar = A + (size_t)l*SS;
    Ar[s1] = a1;
    if (has2) Ar[s2] = a2;
  }
  float w1 = a1 + ((s1 == 0) ? endv[0] : NEGV);
  float w2 = has2 ? (a2 + ((s2 == 100) ? endv[100] : NEGV)) : NINF;
  float M = wave_max_f(fmaxf(w1, w2));
  float P = wave_sum_f(expf(w1 - M) + expf(w2 - M));
  if (lane == 0) LOGZ[b] = M + logf(P);
}

// ---------------- CRF backward+probs (blocks 0..31) and Viterbi (blocks 32..63) ----------------
__global__ __launch_bounds__(64)
void crf_bv_k(const float* __restrict__ EM, const float* __restrict__ AL,
              const float* __restrict__ LOGZ, const float* __restrict__ T,
              const float* __restrict__ startv, const float* __restrict__ endv,
              float* __restrict__ probs, float* __restrict__ paths, float* __restrict__ pprobs)
{
  __shared__ unsigned int lptr[LL];
  const int lane = threadIdx.x;
  const int s1 = lane, s2 = 64 + lane;
  const bool has2 = lane < 37;
  if (blockIdx.x < 32) {
    const int b = blockIdx.x;
    const float* E = EM + (size_t)b*LL*SS;
    const float* A = AL + (size_t)b*LL*SS;
    float* PR = probs + (size_t)b*LL*SS;
    float tn1 = T[s1*101 + s1 + 1];
    float tj1 = (s1 >= 4) ? T[s1*101 + 100] : 0.f;
    float tn2 = (has2 && s2 <= 99) ? T[s2*101 + s2 + 1] : 0.f;
    float tj2 = (has2 && s2 <= 98) ? T[s2*101 + 100] : 0.f;
    float t00 = T[0];
    float t9999 = T[99*101 + 99];
    float t100_0 = T[100*101 + 0], t100_1 = T[100*101 + 1];
    float b1 = (s1 == 0) ? endv[0] : NEGV;
    float b2 = has2 ? ((s2 == 100) ? endv[100] : NEGV) : NINF;
    {
      float w1 = A[(size_t)1023*SS + s1] + b1;
      float w2 = has2 ? (A[(size_t)1023*SS + s2] + b2) : NINF;
      float M = wave_max_f(fmaxf(w1, w2));
      float p1 = expf(w1 - M), p2 = has2 ? expf(w2 - M) : 0.f;
      float Z = wave_sum_f(p1 + p2);
      PR[(size_t)1023*SS + s1] = p1 / Z;
      if (has2) PR[(size_t)1023*SS + s2] = p2 / Z;
    }
    for (int l = 1023; l >= 1; --l) {
      float u1 = E[(size_t)l*SS + s1] + b1;
      float u2 = has2 ? (E[(size_t)l*SS + s2] + b2) : NINF;
      float un1 = __shfl_down(u1, 1);
      float un2 = __shfl_down(u2, 1);
      float u64v = __shfl(u2, 0);
      float u99  = __shfl(u2, 35);
      float u100 = __shfl(u2, 36);
      float u0s  = __shfl(u1, 0);
      float u1s  = __shfl(u1, 1);
      float nb1;
      if (s1 == 0) nb1 = lse2f(t00 + u0s, tn1 + u1s);
      else if (s1 <= 3) nb1 = tn1 + un1;
      else if (s1 <= 62) nb1 = lse2f(tn1 + un1, tj1 + u100);
      else nb1 = lse2f(tn1 + u64v, tj1 + u100);
      float nb2 = NINF;
      if (has2) {
        if (s2 <= 98) nb2 = lse2f(tn2 + un2, tj2 + u100);
        else if (s2 == 99) nb2 = lse2f(t9999 + u99, tn2 + u100);
        else nb2 = lse2f(t100_0 + u0s, t100_1 + u1s);
      }
      b1 = nb1; b2 = has2 ? nb2 : NINF;
      float w1 = A[(size_t)(l-1)*SS + s1] + b1;
      float w2 = has2 ? (A[(size_t)(l-1)*SS + s2] + b2) : NINF;
      float M = wave_max_f(fmaxf(w1, w2));
      float p1 = expf(w1 - M), p2 = has2 ? expf(w2 - M) : 0.f;
      float Z = wave_sum_f(p1 + p2);
      PR[(size_t)(l-1)*SS + s1] = p1 / Z;
      if (has2) PR[(size_t)(l-1)*SS + s2] = p2 / Z;
    }
  } else {
    const int b = blockIdx.x - 32;
    const float* E = EM + (size_t)b*LL*SS;
    float ta1, tb1 = 0.f, tc1 = NINF, ta2 = 0.f, tb2 = 0.f, tc2 = NINF;
    if (s1 == 0)      { ta1 = T[0]; tb1 = T[100*101 + 0]; }
    else if (s1 == 1) { ta1 = T[1]; tb1 = T[100*101 + 1]; }
    else ta1 = T[(s1-1)*101 + s1];
    if (s1 >= 4) tc1 = T[s1*101 + 100];
    if (has2) {
      if (s2 <= 98) ta2 = T[(s2-1)*101 + s2];
      else if (s2 == 99) { ta2 = T[98*101 + 99]; tb2 = T[99*101 + 99]; }
      if (s2 <= 99) tc2 = T[s2*101 + 100];
    }
    float v1 = startv[s1] + E[s1];
    float v2 = has2 ? (startv[s2] + E[s2]) : NINF;
    for (int l = 1; l < LL; ++l) {
      const float* e = E + (size_t)l*SS;
      float c1 = (s1 >= 4) ? v1 + tc1 : NINF;
      float c2 = (has2 && s2 <= 99) ? v2 + tc2 : NINF;
      float bv; int bi;
      if (c2 > c1) { bv = c2; bi = s2; } else { bv = c1; bi = s1; }
      #pragma unroll
      for (int d = 1; d < 64; d <<= 1) {
        float ov = __shfl_xor(bv, d);
        int oi = __shfl_xor(bi, d);
        if (ov > bv || (ov == bv && oi < bi)) { bv = ov; bi = oi; }
      }
      float v1m1 = __shfl_up(v1, 1);
      float v2m1 = __shfl_up(v2, 1);
      float v1t  = __shfl(v1, 63);
      float v0s  = __shfl(v1, 0);
      float v100 = __shfl(v2, 36);
      float n1; int p1i;
      if (s1 <= 1) {
        float x0 = v0s + ta1, x1 = v100 + tb1;
        if (x1 > x0) { n1 = x1; p1i = 100; } else { n1 = x0; p1i = 0; }
      } else { n1 = v1m1 + ta1; p1i = s1 - 1; }
      float n2 = NINF; int p2i = 0;
      if (has2) {
        if (s2 == 64) { n2 = v1t + ta2; p2i = 63; }
        else if (s2 <= 98) { n2 = v2m1 + ta2; p2i = s2 - 1; }
        else if (s2 == 99) {
          float x98 = v2m1 + ta2, x99 = v2 + tb2;
          if (x99 > x98) { n2 = x99; p2i = 99; } else { n2 = x98; p2i = 98; }
        } else { n2 = bv; p2i = bi; }
      }
      v1 = n1 + e[s1];
      v2 = has2 ? (n2 + e[s2]) : NINF;
      int q0   = __shfl(p1i, 0);
      int q1   = __shfl(p1i, 1);
      int q99  = __shfl(p2i, 35);
      int q100 = __shfl(p2i, 36);
      if (lane == 0)
        lptr[l] = (unsigned)q0 | ((unsigned)q1 << 8) | ((unsigned)q99 << 16) | ((unsigned)q100 << 24);
    }
    float w1 = v1 + ((s1 == 0) ? endv[0] : NEGV);
    float w2 = has2 ? (v2 + ((s2 == 100) ? endv[100] : NEGV)) : NINF;
    float bv; int bi;
    if (w2 > w1) { bv = w2; bi = s2; } else { bv = w1; bi = s1; }
    #pragma unroll
    for (int d = 1; d < 64; d <<= 1) {
      float ov = __shfl_xor(bv, d);
      int oi = __shfl_xor(bi, d);
      if (ov > bv || (ov == bv && oi < bi)) { bv = ov; bi = oi; }
    }
    int last = bi; float best = bv;
    if (lane == 0) pprobs[b] = expf(best - LOGZ[b]);
    __syncthreads();
    float* po = paths + (size_t)b*LL;
    int st = last;
    for (int ch = 15; ch >= 0; --ch) {
      unsigned pk = lptr[ch*64 + lane];
      int myval = 0;
      #pragma unroll 1
      for (int j = 63; j >= 0; --j) {
        int t = ch*64 + j;
        if (t >= 1) {
          unsigned pp = __shfl((int)pk, j);
          int prev;
          if (st >= 2 && st <= 98) prev = st - 1;
          else if (st == 0)  prev = (int)(pp & 0xffu);
          else if (st == 1)  prev = (int)((pp >> 8) & 0xffu);
          else if (st == 99) prev = (int)((pp >> 16) & 0xffu);
          else               prev = (int)((pp >> 24) & 0xffu);
          if (j == lane) myval = prev;
          st = prev;
        }
      }
      int ii = ch*64 + lane;
      if (ii >= 1) po[ii - 1] = (float)myval;
    }
    if (lane == 0) po[1023] = (float)last;
  }
}

extern "C" void kernel_launch(void* const* d_in, const int* in_sizes, int n_in,
                              void* d_out, int out_size, void* d_ws, size_t ws_size,
                              hipStream_t stream)
{
  (void)in_sizes; (void)n_in; (void)out_size; (void)ws_size;
  const float* emb      = (const float*)d_in[0];
  const float* W_bneck  = (const float*)d_in[3];
  const float* b_bneck  = (const float*)d_in[4];
  const float* ln_g     = (const float*)d_in[5];
  const float* ln_b     = (const float*)d_in[6];
  const float* conv1_w  = (const float*)d_in[7];
  const float* conv1_b  = (const float*)d_in[8];
  const float* Wih_f    = (const float*)d_in[9];
  const float* Whh_f    = (const float*)d_in[10];
  const float* bih_f    = (const float*)d_in[11];
  const float* bhh_f    = (const float*)d_in[12];
  const float* Wih_b    = (const float*)d_in[13];
  const float* Whh_b    = (const float*)d_in[14];
  const float* bih_b    = (const float*)d_in[15];
  const float* bhh_b    = (const float*)d_in[16];
  const float* conv2_w  = (const float*)d_in[17];
  const float* conv2_b  = (const float*)d_in[18];
  const float* W_emis   = (const float*)d_in[19];
  const float* b_emis   = (const float*)d_in[20];
  const float* crf_trans= (const float*)d_in[21];
  const float* crf_start= (const float*)d_in[22];
  const float* crf_end  = (const float*)d_in[23];
  float* ws = (float*)d_ws;
  float* out = (float*)d_out;

  dim3 b256(256);
  // 1. prep small tensors
  prep_k<<<dim3(7236), b256, 0, stream>>>(Wih_f, Wih_b, bih_f, bhh_f, bih_b, bhh_b,
                                          conv1_w, conv2_w, ws);
  // 2. bottleneck GEMM (transpose + PE fused), bias in epilogue
  gemm_tpl<64,256,0,0,false><<<dim3(512,1), b256, 0, stream>>>(
      nullptr, W_bneck, b_bneck, ws + OFF_X2, ws + OFF_PE, emb, 32768, 256, 1536, 0);
  // 3. LayerNorm + ReLU in-place
  ln_relu_k<<<dim3(8192), b256, 0, stream>>>(ws + OFF_X2, ln_g, ln_b);
  // 4. conv1 as im2col GEMM (K = 3*256), bias+relu
  gemm_tpl<256,64,2,1,true><<<dim3(128,1), b256, 0, stream>>>(
      ws + OFF_X2, ws + OFF_W1R, conv1_b, ws + OFF_X3, nullptr, nullptr, 32768, 64, 768, 256);
  // 5. LSTM input projections (both dirs)
  gemm_tpl<64,256,1,0,false><<<dim3(512,2), b256, 0, stream>>>(
      ws + OFF_X3, ws + OFF_WT_F, ws + OFF_BS_F, ws + OFF_GF, nullptr, nullptr, 32768, 512, 64, 64);
  gemm_tpl<64,256,1,0,false><<<dim3(512,2), b256, 0, stream>>>(
      ws + OFF_X3, ws + OFF_WT_B, ws + OFF_BS_B, ws + OFF_GB, nullptr, nullptr, 32768, 512, 64, 64);
  // 6. LSTM recurrence (fwd + bwd concurrently), writes Hcat over X2
  lstm_k<<<dim3(32,2), dim3(512), 0, stream>>>(ws + OFF_GF, ws + OFF_GB, Whh_f, Whh_b, ws + OFF_X2);
  // 7. conv2 as im2col GEMM (K = 5*256), bias+relu
  gemm_tpl<128,128,2,2,true><<<dim3(256,1), b256, 0, stream>>>(
      ws + OFF_X2, ws + OFF_W2R, conv2_b, ws + OFF_F2, nullptr, nullptr, 32768, 128, 1280, 256);
  // 8. emissions + repeat to 101 states
  emis_k<<<dim3(8192), b256, 0, stream>>>(ws + OFF_F2, W_emis, b_emis, ws + OFF_EMIS);
  // 9. CRF forward (alpha, logZ)
  crf_fwd_k<<<dim3(32), dim3(64), 0, stream>>>(ws + OFF_EMIS, crf_trans, crf_start, crf_end,
                                               ws + OFF_ALPHA, ws + OFF_LOGZ);
  // 10. CRF backward+probs (blocks 0-31) and Viterbi+backtrace (blocks 32-63)
  crf_bv_k<<<dim3(64), dim3(64), 0, stream>>>(ws + OFF_EMIS, ws + OFF_ALPHA, ws + OFF_LOGZ,
                                              crf_trans, crf_start, crf_end,
                                              out, out + 3309568, out + 3342336);
}

// Round 2
// 3864.095 us; speedup vs baseline: 1.8376x; 1.8376x over previous
//
#include <hip/hip_runtime.h>
#include <cstdint>
#include <cstddef>

// Problem constants
#define BB 32
#define LL 1024
#define DD 1536
#define SS 101
#define NEGV (-1e4f)
#define NINF (-1e30f)
#define L2E 1.4426950408889634f
#define LN2 0.6931471805599453f

// workspace layout (float offsets)
#define NPE   (1024*1536)
#define NX2   (32768*256)
#define NX3   (32768*64)
#define NG    (32768*512)
#define NF2   (32768*128)
#define NEM   (32768*101)

#define OFF_PE    0
#define OFF_X2    (OFF_PE + NPE)        // Y1 -> X2 (in-place LN) -> later Hcat
#define OFF_X3    (OFF_X2 + NX2)
#define OFF_GF    (OFF_X3 + NX3)
#define OFF_GB    (OFF_GF + NG)
#define OFF_F2    (OFF_GF)              // reuse GF after LSTM
#define OFF_EMIS  (OFF_GF + NF2)
#define OFF_ALPHA (OFF_EMIS + NEM)
#define OFF_LOGZ  (OFF_ALPHA + NEM)
#define OFF_VBEST (OFF_LOGZ + 64)
#define OFF_WT_F  (OFF_GB + NG)
#define OFF_WT_B  (OFF_WT_F + 32768)
#define OFF_BS_F  (OFF_WT_B + 32768)
#define OFF_BS_B  (OFF_BS_F + 512)
#define OFF_W1R   (OFF_BS_B + 512)
#define OFF_W2R   (OFF_W1R + 49152)

// ---------------- prep: PE (transposed [k][l]), Wih^T, bias sums, conv weights rearranged t-major ----------------
__global__ __launch_bounds__(256)
void prep_k(const float* __restrict__ Wihf, const float* __restrict__ Wihb,
            const float* __restrict__ bihf, const float* __restrict__ bhhf,
            const float* __restrict__ bihb, const float* __restrict__ bhhb,
            const float* __restrict__ w1, const float* __restrict__ w2,
            float* __restrict__ ws)
{
  int idx = blockIdx.x * 256 + threadIdx.x;
  if (idx < NPE) {
    int k = idx >> 10, l = idx & 1023;
    int j2 = (k >> 1) * 2;
    float freq = expf((float)j2 * (-9.210340371976184f / 1536.f));
    float ang = (float)l * freq;
    ws[OFF_PE + idx] = (k & 1) ? cosf(ang) : sinf(ang);
    return;
  }
  idx -= NPE;
  if (idx < 32768) { int k = idx >> 9, n = idx & 511; ws[OFF_WT_F + idx] = Wihf[n*64 + k]; return; }
  idx -= 32768;
  if (idx < 32768) { int k = idx >> 9, n = idx & 511; ws[OFF_WT_B + idx] = Wihb[n*64 + k]; return; }
  idx -= 32768;
  if (idx < 512) { ws[OFF_BS_F + idx] = bihf[idx] + bhhf[idx]; return; }
  idx -= 512;
  if (idx < 512) { ws[OFF_BS_B + idx] = bihb[idx] + bhhb[idx]; return; }
  idx -= 512;
  if (idx < 49152) {  // w1r[(t*256+c)*64+f] = w1[f][c][t]
    int f = idx & 63, tc = idx >> 6;
    int t = tc >> 8, c = tc & 255;
    ws[OFF_W1R + idx] = w1[(f*256 + c)*3 + t];
    return;
  }
  idx -= 49152;
  if (idx < 163840) { // w2r[(t*256+c)*128+f] = w2[f][c][t]
    int f = idx & 127, tc = idx >> 7;
    int t = tc >> 8, c = tc & 255;
    ws[OFF_W2R + idx] = w2[(f*256 + c)*5 + t];
  }
}

// ---------------- generic fp32 tiled GEMM ----------------
template<int BM, int BN, int AMODE, int PADT, bool RELU>
__global__ __launch_bounds__(256)
void gemm_tpl(const float* __restrict__ Ap, const float* __restrict__ Bp,
              const float* __restrict__ biasp, float* __restrict__ Cp,
              const float* __restrict__ PEp, const float* __restrict__ EMBp,
              int M, int N, int K, int lda)
{
  constexpr int BK = 16;
  __shared__ __align__(16) float As[BK][BM + 4];
  __shared__ __align__(16) float Bs[BK][BN];
  constexpr int TX = BN / 8, TY = BM / 8;
  const int tid = threadIdx.x;
  const int tx = tid % TX, ty = tid / TX;
  const int m0 = blockIdx.x * BM;
  const int n0 = blockIdx.y * BN;
  float acc[8][8];
  #pragma unroll
  for (int i = 0; i < 8; i++)
    #pragma unroll
    for (int j = 0; j < 8; j++) acc[i][j] = 0.f;

  for (int k0 = 0; k0 < K; k0 += BK) {
    if constexpr (AMODE == 0) {
      #pragma unroll
      for (int i = 0; i < (BK*BM)/256; ++i) {
        int e = tid + i*256;
        int ml = e % BM, kk = e / BM;
        int row = m0 + ml; int b = row >> 10; int l = row & 1023;
        int k = k0 + kk;
        As[kk][ml] = EMBp[((size_t)b*DD + k)*LL + l] + PEp[(size_t)k*LL + l];
      }
    } else {
      #pragma unroll
      for (int i = 0; i < (BK*BM)/256; ++i) {
        int e = tid + i*256;
        int kk = e % BK, ml = e / BK;
        int row = m0 + ml; int k = k0 + kk;
        float v;
        if constexpr (AMODE == 1) {
          v = Ap[(size_t)row*lda + k];
        } else {
          int c = k & 255, t = k >> 8;
          int l = row & 1023, sl = l + t - PADT;
          v = ((unsigned)sl < 1024u) ? Ap[(size_t)(row + t - PADT)*lda + c] : 0.f;
        }
        As[kk][ml] = v;
      }
    }
    #pragma unroll
    for (int i = 0; i < (BK*BN)/256; ++i) {
      int e = tid + i*256;
      int nl = e % BN, kk = e / BN;
      Bs[kk][nl] = Bp[(size_t)(k0+kk)*N + n0 + nl];
    }
    __syncthreads();
    #pragma unroll
    for (int k = 0; k < BK; ++k) {
      float4 a0 = *(const float4*)&As[k][ty*4];
      float4 a1 = *(const float4*)&As[k][BM/2 + ty*4];
      float4 b0 = *(const float4*)&Bs[k][tx*4];
      float4 b1 = *(const float4*)&Bs[k][BN/2 + tx*4];
      float av[8] = {a0.x,a0.y,a0.z,a0.w,a1.x,a1.y,a1.z,a1.w};
      float bv[8] = {b0.x,b0.y,b0.z,b0.w,b1.x,b1.y,b1.z,b1.w};
      #pragma unroll
      for (int i = 0; i < 8; i++)
        #pragma unroll
        for (int j = 0; j < 8; j++) acc[i][j] += av[i]*bv[j];
    }
    __syncthreads();
  }
  float4 bias0 = *(const float4*)&biasp[n0 + tx*4];
  float4 bias1 = *(const float4*)&biasp[n0 + BN/2 + tx*4];
  float bn[8] = {bias0.x,bias0.y,bias0.z,bias0.w,bias1.x,bias1.y,bias1.z,bias1.w};
  #pragma unroll
  for (int i = 0; i < 8; i++) {
    int r = m0 + ((i < 4) ? (ty*4 + i) : (BM/2 + ty*4 + i - 4));
    float o[8];
    #pragma unroll
    for (int j = 0; j < 8; j++) {
      float v = acc[i][j] + bn[j];
      o[j] = RELU ? fmaxf(v, 0.f) : v;
    }
    *(float4*)&Cp[(size_t)r*N + n0 + tx*4] = make_float4(o[0],o[1],o[2],o[3]);
    *(float4*)&Cp[(size_t)r*N + n0 + BN/2 + tx*4] = make_float4(o[4],o[5],o[6],o[7]);
  }
}

// ---------------- LayerNorm + ReLU ----------------
__global__ __launch_bounds__(256)
void ln_relu_k(float* __restrict__ X, const float* __restrict__ g, const float* __restrict__ bt)
{
  const int lane = threadIdx.x & 63, wv = threadIdx.x >> 6;
  const size_t row = (size_t)blockIdx.x * 4 + wv;
  float4 v = *(const float4*)&X[row*256 + lane*4];
  float s = v.x + v.y + v.z + v.w;
  float q = v.x*v.x + v.y*v.y + v.z*v.z + v.w*v.w;
  #pragma unroll
  for (int d = 1; d < 64; d <<= 1) { s += __shfl_xor(s, d); q += __shfl_xor(q, d); }
  float mean = s * (1.f/256.f);
  float var = q * (1.f/256.f) - mean*mean;
  float inv = 1.f / sqrtf(var + 1e-5f);
  float4 gg = *(const float4*)&g[lane*4];
  float4 bb = *(const float4*)&bt[lane*4];
  float4 o;
  o.x = fmaxf(0.f, (v.x-mean)*inv*gg.x + bb.x);
  o.y = fmaxf(0.f, (v.y-mean)*inv*gg.y + bb.y);
  o.z = fmaxf(0.f, (v.z-mean)*inv*gg.z + bb.z);
  o.w = fmaxf(0.f, (v.w-mean)*inv*gg.w + bb.w);
  *(float4*)&X[row*256 + lane*4] = o;
}

// ---------------- LSTM recurrence ----------------
__global__ __launch_bounds__(512, 2)
void lstm_k(const float* __restrict__ GF, const float* __restrict__ GB,
            const float* __restrict__ WhhF, const float* __restrict__ WhhB,
            float* __restrict__ Hcat)
{
  const int dir = blockIdx.y;
  const int b = blockIdx.x;
  const int j = threadIdx.x;
  const float* G = dir ? GB : GF;
  const float* Whh = dir ? WhhB : WhhF;
  float w[128];
  #pragma unroll
  for (int i = 0; i < 32; ++i) {
    float4 t4 = *(const float4*)&Whh[(size_t)j*128 + i*4];
    w[4*i] = t4.x; w[4*i+1] = t4.y; w[4*i+2] = t4.z; w[4*i+3] = t4.w;
  }
  __shared__ __align__(16) float hs[128];
  __shared__ float gs[512];
  if (j < 128) hs[j] = 0.f;
  float c = 0.f;
  __syncthreads();
  for (int step = 0; step < LL; ++step) {
    const int l = dir ? (1023 - step) : step;
    float acc = G[((size_t)b*LL + l)*512 + j];
    #pragma unroll
    for (int k = 0; k < 128; k += 4) {
      float4 h4 = *(const float4*)&hs[k];
      acc += h4.x*w[k] + h4.y*w[k+1] + h4.z*w[k+2] + h4.w*w[k+3];
    }
    float gv;
    if (j < 256 || j >= 384) gv = 1.f / (1.f + expf(-acc));  // i, f, o gates
    else gv = tanhf(acc);                                     // g gate
    gs[j] = gv;
    __syncthreads();
    if (j < 128) {
      float ig = gs[j], fg = gs[128+j], g2 = gs[256+j], og = gs[384+j];
      c = fg*c + ig*g2;
      float hh = og * tanhf(c);
      hs[j] = hh;
      Hcat[((size_t)b*LL + l)*256 + (dir << 7) + j] = hh;
    }
    __syncthreads();
  }
}

// ---------------- wave helpers ----------------
__device__ __forceinline__ float wave_sum_f(float v){
  #pragma unroll
  for (int d = 1; d < 64; d <<= 1) v += __shfl_xor(v, d);
  return v;
}
__device__ __forceinline__ float wave_max_f(float v){
  #pragma unroll
  for (int d = 1; d < 64; d <<= 1) v = fmaxf(v, __shfl_xor(v, d));
  return v;
}
__device__ __forceinline__ float rdlanef(float v, int l){
  union { float f; int i; } u; u.f = v;
  u.i = __builtin_amdgcn_readlane(u.i, l);
  return u.f;
}
// fast lse2 via native exp2/log2
__device__ __forceinline__ float lse2f(float x, float y){
  float mx = fmaxf(x, y), mn = fminf(x, y);
  return mx + log2f(1.f + exp2f((mn - mx) * L2E)) * LN2;
}

// ---------------- emissions: wave per position ----------------
__global__ __launch_bounds__(256)
void emis_k(const float* __restrict__ F2, const float* __restrict__ W,
            const float* __restrict__ bias, float* __restrict__ EM)
{
  const int lane = threadIdx.x & 63;
  const size_t m = (size_t)blockIdx.x * 4 + (threadIdx.x >> 6);
  float f1 = F2[m*128 + lane], f2 = F2[m*128 + 64 + lane];
  float e0 = f1*W[lane*2]   + f2*W[(64+lane)*2];
  float e1 = f1*W[lane*2+1] + f2*W[(64+lane)*2+1];
  e0 = wave_sum_f(e0) + bias[0];
  e1 = wave_sum_f(e1) + bias[1];
  float* row = EM + m*SS;
  row[lane] = (lane == 0) ? e0 : e1;
  if (lane < 37) row[64 + lane] = e1;
}

// ---------------- CRF pass 1: forward (blocks 0-31) + Viterbi (blocks 32-63) ----------------
__global__ __launch_bounds__(64)
void crf1_k(const float* __restrict__ EM, const float* __restrict__ T,
            const float* __restrict__ startv, const float* __restrict__ endv,
            float* __restrict__ AL, float* __restrict__ LOGZ,
            float* __restrict__ paths, float* __restrict__ vbest)
{
  __shared__ unsigned int lptr[LL];
  const int lane = threadIdx.x;
  const int s1 = lane, s2 = 64 + lane;
  const bool has2 = lane < 37;
  // per-lane transition constants (same derivation as verified round-1 kernel)
  float ta1, tb1 = 0.f, tc1 = NINF, ta2 = 0.f, tb2 = 0.f, tc2 = NINF;
  if (s1 == 0)      { ta1 = T[0]; tb1 = T[100*101 + 0]; }
  else if (s1 == 1) { ta1 = T[1]; tb1 = T[100*101 + 1]; }
  else ta1 = T[(s1-1)*101 + s1];
  if (s1 >= 4) tc1 = T[s1*101 + 100];
  if (has2) {
    if (s2 <= 98) ta2 = T[(s2-1)*101 + s2];
    else if (s2 == 99) { ta2 = T[98*101 + 99]; tb2 = T[99*101 + 99]; }
    if (s2 <= 99) tc2 = T[s2*101 + 100];
  }

  if (blockIdx.x < 32) {
    // ---------- forward ----------
    const int b = blockIdx.x;
    const float* E = EM + (size_t)b*LL*SS;
    float* A = AL + (size_t)b*LL*SS;
    float a1 = startv[s1] + E[s1];
    float a2 = has2 ? (startv[s2] + E[s2]) : NINF;
    A[s1] = a1;
    if (has2) A[s2] = a2;
    // exact initial shift M (butterfly once)
    float M;
    {
      float v1 = a1 + tc1;
      float v2 = a2 + tc2;
      M = wave_max_f(fmaxf(v1, v2));
    }
    auto fstep = [&](int l, float e1, float e2) {
      float v1 = a1 + tc1;
      float v2 = a2 + tc2;
      float p = exp2f((v1 - M) * L2E) + exp2f((v2 - M) * L2E);
      p = fmaxf(wave_sum_f(p), 1e-37f);
      float lse100 = M + log2f(p) * LN2;
      float a1m1 = __shfl_up(a1, 1);
      float a2m1 = __shfl_up(a2, 1);
      float a1t  = rdlanef(a1, 63);
      float a0s  = rdlanef(a1, 0);
      float a100 = rdlanef(a2, 36);
      float n1 = (s1 <= 1) ? lse2f(a0s + ta1, a100 + tb1) : (a1m1 + ta1);
      float n2;
      if (s2 == 64) n2 = a1t + ta2;
      else if (s2 <= 98) n2 = a2m1 + ta2;
      else if (s2 == 99) n2 = lse2f(a2m1 + ta2, a2 + tb2);
      else n2 = lse100;
      a1 = n1 + e1;
      a2 = has2 ? (n2 + e2) : NINF;
      float* Ar = A + (size_t)l*SS;
      Ar[s1] = a1;
      if (has2) Ar[s2] = a2;
      M = lse100;   // approximate shift for next step (within exp range; see clamp)
    };
    int l = 1;
    for (; l + 3 < LL; l += 4) {
      float e1a[4], e2a[4];
      #pragma unroll
      for (int u = 0; u < 4; ++u) {
        const float* e = E + (size_t)(l+u)*SS;
        e1a[u] = e[s1]; e2a[u] = has2 ? e[s2] : 0.f;
      }
      #pragma unroll
      for (int u = 0; u < 4; ++u) fstep(l+u, e1a[u], e2a[u]);
    }
    for (; l < LL; ++l) {
      const float* e = E + (size_t)l*SS;
      fstep(l, e[s1], has2 ? e[s2] : 0.f);
    }
    float w1 = a1 + ((s1 == 0) ? endv[0] : NEGV);
    float w2 = has2 ? (a2 + ((s2 == 100) ? endv[100] : NEGV)) : NINF;
    float Mx = wave_max_f(fmaxf(w1, w2));
    float P = wave_sum_f(exp2f((w1 - Mx) * L2E) + exp2f((w2 - Mx) * L2E));
    if (lane == 0) LOGZ[b] = Mx + log2f(P) * LN2;
  } else {
    // ---------- Viterbi ----------
    const int b = blockIdx.x - 32;
    const float* E = EM + (size_t)b*LL*SS;
    float v1 = startv[s1] + E[s1];
    float v2 = has2 ? (startv[s2] + E[s2]) : NINF;
    auto vstep = [&](int l, float e1, float e2) {
      float c1 = v1 + tc1;
      float c2 = v2 + tc2;
      float Mx = wave_max_f(fmaxf(c1, c2));
      unsigned long long m1 = __ballot(c1 == Mx);
      int bi;
      if (m1 != 0ULL) bi = __ffsll((unsigned long long)m1) - 1;
      else bi = 64 + __ffsll((unsigned long long)__ballot(c2 == Mx)) - 1;
      float v1m1 = __shfl_up(v1, 1);
      float v2m1 = __shfl_up(v2, 1);
      float v1t  = rdlanef(v1, 63);
      float v0s  = rdlanef(v1, 0);
      float v100 = rdlanef(v2, 36);
      float n1; int p1i;
      if (s1 <= 1) {
        float x0 = v0s + ta1, x1 = v100 + tb1;
        if (x1 > x0) { n1 = x1; p1i = 100; } else { n1 = x0; p1i = 0; }
      } else { n1 = v1m1 + ta1; p1i = s1 - 1; }
      float n2 = NINF; int p2i = 0;
      if (has2) {
        if (s2 == 64) { n2 = v1t + ta2; p2i = 63; }
        else if (s2 <= 98) { n2 = v2m1 + ta2; p2i = s2 - 1; }
        else if (s2 == 99) {
          float x98 = v2m1 + ta2, x99 = v2 + tb2;
          if (x99 > x98) { n2 = x99; p2i = 99; } else { n2 = x98; p2i = 98; }
        } else { n2 = Mx; p2i = bi; }
      }
      v1 = n1 + e1;
      v2 = has2 ? (n2 + e2) : NINF;
      int q0   = __builtin_amdgcn_readlane(p1i, 0);
      int q1   = __builtin_amdgcn_readlane(p1i, 1);
      int q99  = __builtin_amdgcn_readlane(p2i, 35);
      int q100 = __builtin_amdgcn_readlane(p2i, 36);
      if (lane == 0)
        lptr[l] = (unsigned)q0 | ((unsigned)q1 << 8) | ((unsigned)q99 << 16) | ((unsigned)q100 << 24);
    };
    int l = 1;
    for (; l + 3 < LL; l += 4) {
      float e1a[4], e2a[4];
      #pragma unroll
      for (int u = 0; u < 4; ++u) {
        const float* e = E + (size_t)(l+u)*SS;
        e1a[u] = e[s1]; e2a[u] = has2 ? e[s2] : 0.f;
      }
      #pragma unroll
      for (int u = 0; u < 4; ++u) vstep(l+u, e1a[u], e2a[u]);
    }
    for (; l < LL; ++l) {
      const float* e = E + (size_t)l*SS;
      vstep(l, e[s1], has2 ? e[s2] : 0.f);
    }
    float w1 = v1 + ((s1 == 0) ? endv[0] : NEGV);
    float w2 = has2 ? (v2 + ((s2 == 100) ? endv[100] : NEGV)) : NINF;
    float Mx = wave_max_f(fmaxf(w1, w2));
    unsigned long long m1 = __ballot(w1 == Mx);
    int last;
    if (m1 != 0ULL) last = __ffsll((unsigned long long)m1) - 1;
    else last = 64 + __ffsll((unsigned long long)__ballot(w2 == Mx)) - 1;
    if (lane == 0) vbest[b] = Mx;
    __syncthreads();
    float* po = paths + (size_t)b*LL;
    int st = last;
    for (int ch = 15; ch >= 0; --ch) {
      unsigned pk = lptr[ch*64 + lane];
      int myval = 0;
      #pragma unroll 1
      for (int j = 63; j >= 0; --j) {
        int t = ch*64 + j;
        if (t >= 1) {
          unsigned pp = __shfl((int)pk, j);
          int prev;
          if (st >= 2 && st <= 98) prev = st - 1;
          else if (st == 0)  prev = (int)(pp & 0xffu);
          else if (st == 1)  prev = (int)((pp >> 8) & 0xffu);
          else if (st == 99) prev = (int)((pp >> 16) & 0xffu);
          else               prev = (int)((pp >> 24) & 0xffu);
          if (j == lane) myval = prev;
          st = prev;
        }
      }
      int ii = ch*64 + lane;
      if (ii >= 1) po[ii - 1] = (float)myval;
    }
    if (lane == 0) po[1023] = (float)last;
  }
}

// ---------------- CRF pass 2: backward, write UNNORMALIZED alpha+beta ----------------
__global__ __launch_bounds__(64)
void crf_bwd_k(const float* __restrict__ EM, const float* __restrict__ AL,
               const float* __restrict__ T, const float* __restrict__ endv,
               float* __restrict__ U)
{
  const int b = blockIdx.x, lane = threadIdx.x;
  const int s1 = lane, s2 = 64 + lane;
  const bool has2 = lane < 37;
  const float* E = EM + (size_t)b*LL*SS;
  const float* A = AL + (size_t)b*LL*SS;
  float* PR = U + (size_t)b*LL*SS;
  float tn1 = T[s1*101 + s1 + 1];
  float tj1 = (s1 >= 4) ? T[s1*101 + 100] : 0.f;
  float tn2 = (has2 && s2 <= 99) ? T[s2*101 + s2 + 1] : 0.f;
  float tj2 = (has2 && s2 <= 98) ? T[s2*101 + 100] : 0.f;
  float t00 = T[0];
  float t9999 = T[99*101 + 99];
  float t100_0 = T[100*101 + 0], t100_1 = T[100*101 + 1];
  float b1 = (s1 == 0) ? endv[0] : NEGV;
  float b2 = has2 ? ((s2 == 100) ? endv[100] : NEGV) : NINF;
  PR[(size_t)1023*SS + s1] = A[(size_t)1023*SS + s1] + b1;
  if (has2) PR[(size_t)1023*SS + s2] = A[(size_t)1023*SS + s2] + b2;
  auto bstep = [&](int l, float e1, float e2, float a1r, float a2r) {
    float u1 = e1 + b1;
    float u2 = has2 ? (e2 + b2) : NINF;
    float un1 = __shfl_down(u1, 1);
    float un2 = __shfl_down(u2, 1);
    float u64v = rdlanef(u2, 0);
    float u99  = rdlanef(u2, 35);
    float u100 = rdlanef(u2, 36);
    float u0s  = rdlanef(u1, 0);
    float u1s  = rdlanef(u1, 1);
    float nb1;
    if (s1 == 0) nb1 = lse2f(t00 + u0s, tn1 + u1s);
    else if (s1 <= 3) nb1 = tn1 + un1;
    else if (s1 <= 62) nb1 = lse2f(tn1 + un1, tj1 + u100);
    else nb1 = lse2f(tn1 + u64v, tj1 + u100);
    float nb2 = NINF;
    if (has2) {
      if (s2 <= 98) nb2 = lse2f(tn2 + un2, tj2 + u100);
      else if (s2 == 99) nb2 = lse2f(t9999 + u99, tn2 + u100);
      else nb2 = lse2f(t100_0 + u0s, t100_1 + u1s);
    }
    b1 = nb1; b2 = has2 ? nb2 : NINF;
    PR[(size_t)(l-1)*SS + s1] = a1r + b1;
    if (has2) PR[(size_t)(l-1)*SS + s2] = a2r + b2;
  };
  int l = 1023;
  for (; l >= 4; l -= 4) {
    float e1a[4], e2a[4], a1a[4], a2a[4];
    #pragma unroll
    for (int u = 0; u < 4; ++u) {
      const float* e = E + (size_t)(l-u)*SS;
      const float* a = A + (size_t)(l-1-u)*SS;
      e1a[u] = e[s1]; e2a[u] = has2 ? e[s2] : 0.f;
      a1a[u] = a[s1]; a2a[u] = has2 ? a[s2] : 0.f;
    }
    #pragma unroll
    for (int u = 0; u < 4; ++u) bstep(l-u, e1a[u], e2a[u], a1a[u], a2a[u]);
  }
  for (; l >= 1; --l) {
    const float* e = E + (size_t)l*SS;
    const float* a = A + (size_t)(l-1)*SS;
    bstep(l, e[s1], has2 ? e[s2] : 0.f, a[s1], has2 ? a[s2] : 0.f);
  }
}

// ---------------- CRF pass 3: massively-parallel row softmax + pprobs ----------------
__global__ __launch_bounds__(256)
void crf_norm_k(float* __restrict__ PR, const float* __restrict__ vbest,
                const float* __restrict__ LOGZ, float* __restrict__ pprobs)
{
  const int lane = threadIdx.x & 63;
  const size_t m = (size_t)blockIdx.x * 4 + (threadIdx.x >> 6);
  float* row = PR + m*SS;
  float w1 = row[lane];
  float w2 = (lane < 37) ? row[64 + lane] : NINF;
  float M = wave_max_f(fmaxf(w1, w2));
  float p1 = exp2f((w1 - M) * L2E);
  float p2 = (lane < 37) ? exp2f((w2 - M) * L2E) : 0.f;
  float Z = wave_sum_f(p1 + p2);
  float rz = 1.f / Z;
  row[lane] = p1 * rz;
  if (lane < 37) row[64 + lane] = p2 * rz;
  if (blockIdx.x == 0 && threadIdx.x < 32)
    pprobs[threadIdx.x] = exp2f((vbest[threadIdx.x] - LOGZ[threadIdx.x]) * L2E);
}

extern "C" void kernel_launch(void* const* d_in, const int* in_sizes, int n_in,
                              void* d_out, int out_size, void* d_ws, size_t ws_size,
                              hipStream_t stream)
{
  (void)in_sizes; (void)n_in; (void)out_size; (void)ws_size;
  const float* emb      = (const float*)d_in[0];
  const float* W_bneck  = (const float*)d_in[3];
  const float* b_bneck  = (const float*)d_in[4];
  const float* ln_g     = (const float*)d_in[5];
  const float* ln_b     = (const float*)d_in[6];
  const float* conv1_w  = (const float*)d_in[7];
  const float* conv1_b  = (const float*)d_in[8];
  const float* Wih_f    = (const float*)d_in[9];
  const float* Whh_f    = (const float*)d_in[10];
  const float* bih_f    = (const float*)d_in[11];
  const float* bhh_f    = (const float*)d_in[12];
  const float* Wih_b    = (const float*)d_in[13];
  const float* Whh_b    = (const float*)d_in[14];
  const float* bih_b    = (const float*)d_in[15];
  const float* bhh_b    = (const float*)d_in[16];
  const float* conv2_w  = (const float*)d_in[17];
  const float* conv2_b  = (const float*)d_in[18];
  const float* W_emis   = (const float*)d_in[19];
  const float* b_emis   = (const float*)d_in[20];
  const float* crf_trans= (const float*)d_in[21];
  const float* crf_start= (const float*)d_in[22];
  const float* crf_end  = (const float*)d_in[23];
  float* ws = (float*)d_ws;
  float* out = (float*)d_out;

  dim3 b256(256);
  // 1. prep small tensors
  prep_k<<<dim3(7236), b256, 0, stream>>>(Wih_f, Wih_b, bih_f, bhh_f, bih_b, bhh_b,
                                          conv1_w, conv2_w, ws);
  // 2. bottleneck GEMM (transpose + PE fused), bias in epilogue
  gemm_tpl<64,256,0,0,false><<<dim3(512,1), b256, 0, stream>>>(
      nullptr, W_bneck, b_bneck, ws + OFF_X2, ws + OFF_PE, emb, 32768, 256, 1536, 0);
  // 3. LayerNorm + ReLU in-place
  ln_relu_k<<<dim3(8192), b256, 0, stream>>>(ws + OFF_X2, ln_g, ln_b);
  // 4. conv1 as im2col GEMM (K = 3*256), bias+relu
  gemm_tpl<256,64,2,1,true><<<dim3(128,1), b256, 0, stream>>>(
      ws + OFF_X2, ws + OFF_W1R, conv1_b, ws + OFF_X3, nullptr, nullptr, 32768, 64, 768, 256);
  // 5. LSTM input projections (both dirs)
  gemm_tpl<64,256,1,0,false><<<dim3(512,2), b256, 0, stream>>>(
      ws + OFF_X3, ws + OFF_WT_F, ws + OFF_BS_F, ws + OFF_GF, nullptr, nullptr, 32768, 512, 64, 64);
  gemm_tpl<64,256,1,0,false><<<dim3(512,2), b256, 0, stream>>>(
      ws + OFF_X3, ws + OFF_WT_B, ws + OFF_BS_B, ws + OFF_GB, nullptr, nullptr, 32768, 512, 64, 64);
  // 6. LSTM recurrence (fwd + bwd concurrently), writes Hcat over X2
  lstm_k<<<dim3(32,2), dim3(512), 0, stream>>>(ws + OFF_GF, ws + OFF_GB, Whh_f, Whh_b, ws + OFF_X2);
  // 7. conv2 as im2col GEMM (K = 5*256), bias+relu
  gemm_tpl<128,128,2,2,true><<<dim3(256,1), b256, 0, stream>>>(
      ws + OFF_X2, ws + OFF_W2R, conv2_b, ws + OFF_F2, nullptr, nullptr, 32768, 128, 1280, 256);
  // 8. emissions + repeat to 101 states
  emis_k<<<dim3(8192), b256, 0, stream>>>(ws + OFF_F2, W_emis, b_emis, ws + OFF_EMIS);
  // 9. CRF pass 1: forward (blocks 0-31) + Viterbi+backtrace (blocks 32-63), concurrent
  crf1_k<<<dim3(64), dim3(64), 0, stream>>>(ws + OFF_EMIS, crf_trans, crf_start, crf_end,
                                            ws + OFF_ALPHA, ws + OFF_LOGZ,
                                            out + 3309568, ws + OFF_VBEST);
  // 10. CRF pass 2: backward, unnormalized alpha+beta into probs area
  crf_bwd_k<<<dim3(32), dim3(64), 0, stream>>>(ws + OFF_EMIS, ws + OFF_ALPHA,
                                               crf_trans, crf_end, out);
  // 11. CRF pass 3: row softmax + path probs
  crf_norm_k<<<dim3(8192), b256, 0, stream>>>(out, ws + OFF_VBEST, ws + OFF_LOGZ,
                                              out + 3342336);
}

// Round 3
// 3181.016 us; speedup vs baseline: 2.2322x; 1.2147x over previous
//
#include <hip/hip_runtime.h>
#include <cstdint>
#include <cstddef>

// Problem constants
#define BB 32
#define LL 1024
#define DD 1536
#define SS 101
#define NEGV (-1e4f)
#define NINF (-1e30f)
#define L2E 1.4426950408889634f
#define LN2 0.6931471805599453f

// workspace layout (float offsets)
#define NPE   (1024*1536)
#define NX2   (32768*256)
#define NX3   (32768*64)
#define NG    (32768*512)
#define NF2   (32768*128)
#define NEM   (32768*101)

#define OFF_PE    0
#define OFF_X2    (OFF_PE + NPE)        // Y1 -> X2 (in-place LN) -> later Hcat
#define OFF_X3    (OFF_X2 + NX2)
#define OFF_GF    (OFF_X3 + NX3)
#define OFF_GB    (OFF_GF + NG)
#define OFF_F2    (OFF_GF)              // reuse GF after LSTM
#define OFF_EMIS  (OFF_GF + NF2)
#define OFF_ALPHA (OFF_EMIS + NEM)
#define OFF_LOGZ  (OFF_ALPHA + NEM)
#define OFF_VBEST (OFF_LOGZ + 64)
#define OFF_WT_F  (OFF_GB + NG)
#define OFF_WT_B  (OFF_WT_F + 32768)
#define OFF_BS_F  (OFF_WT_B + 32768)
#define OFF_BS_B  (OFF_BS_F + 512)
#define OFF_W1R   (OFF_BS_B + 512)
#define OFF_W2R   (OFF_W1R + 49152)

// ---------------- prep: PE (transposed [k][l]), Wih^T, bias sums, conv weights rearranged t-major ----------------
__global__ __launch_bounds__(256)
void prep_k(const float* __restrict__ Wihf, const float* __restrict__ Wihb,
            const float* __restrict__ bihf, const float* __restrict__ bhhf,
            const float* __restrict__ bihb, const float* __restrict__ bhhb,
            const float* __restrict__ w1, const float* __restrict__ w2,
            float* __restrict__ ws)
{
  int idx = blockIdx.x * 256 + threadIdx.x;
  if (idx < NPE) {
    int k = idx >> 10, l = idx & 1023;
    int j2 = (k >> 1) * 2;
    float freq = expf((float)j2 * (-9.210340371976184f / 1536.f));
    float ang = (float)l * freq;
    ws[OFF_PE + idx] = (k & 1) ? cosf(ang) : sinf(ang);
    return;
  }
  idx -= NPE;
  if (idx < 32768) { int k = idx >> 9, n = idx & 511; ws[OFF_WT_F + idx] = Wihf[n*64 + k]; return; }
  idx -= 32768;
  if (idx < 32768) { int k = idx >> 9, n = idx & 511; ws[OFF_WT_B + idx] = Wihb[n*64 + k]; return; }
  idx -= 32768;
  if (idx < 512) { ws[OFF_BS_F + idx] = bihf[idx] + bhhf[idx]; return; }
  idx -= 512;
  if (idx < 512) { ws[OFF_BS_B + idx] = bihb[idx] + bhhb[idx]; return; }
  idx -= 512;
  if (idx < 49152) {  // w1r[(t*256+c)*64+f] = w1[f][c][t]
    int f = idx & 63, tc = idx >> 6;
    int t = tc >> 8, c = tc & 255;
    ws[OFF_W1R + idx] = w1[(f*256 + c)*3 + t];
    return;
  }
  idx -= 49152;
  if (idx < 163840) { // w2r[(t*256+c)*128+f] = w2[f][c][t]
    int f = idx & 127, tc = idx >> 7;
    int t = tc >> 8, c = tc & 255;
    ws[OFF_W2R + idx] = w2[(f*256 + c)*5 + t];
  }
}

// ---------------- generic fp32 tiled GEMM ----------------
template<int BM, int BN, int AMODE, int PADT, bool RELU>
__global__ __launch_bounds__(256)
void gemm_tpl(const float* __restrict__ Ap, const float* __restrict__ Bp,
              const float* __restrict__ biasp, float* __restrict__ Cp,
              const float* __restrict__ PEp, const float* __restrict__ EMBp,
              int M, int N, int K, int lda)
{
  constexpr int BK = 16;
  __shared__ __align__(16) float As[BK][BM + 4];
  __shared__ __align__(16) float Bs[BK][BN];
  constexpr int TX = BN / 8, TY = BM / 8;
  const int tid = threadIdx.x;
  const int tx = tid % TX, ty = tid / TX;
  const int m0 = blockIdx.x * BM;
  const int n0 = blockIdx.y * BN;
  float acc[8][8];
  #pragma unroll
  for (int i = 0; i < 8; i++)
    #pragma unroll
    for (int j = 0; j < 8; j++) acc[i][j] = 0.f;

  for (int k0 = 0; k0 < K; k0 += BK) {
    if constexpr (AMODE == 0) {
      #pragma unroll
      for (int i = 0; i < (BK*BM)/256; ++i) {
        int e = tid + i*256;
        int ml = e % BM, kk = e / BM;
        int row = m0 + ml; int b = row >> 10; int l = row & 1023;
        int k = k0 + kk;
        As[kk][ml] = EMBp[((size_t)b*DD + k)*LL + l] + PEp[(size_t)k*LL + l];
      }
    } else {
      #pragma unroll
      for (int i = 0; i < (BK*BM)/256; ++i) {
        int e = tid + i*256;
        int kk = e % BK, ml = e / BK;
        int row = m0 + ml; int k = k0 + kk;
        float v;
        if constexpr (AMODE == 1) {
          v = Ap[(size_t)row*lda + k];
        } else {
          int c = k & 255, t = k >> 8;
          int l = row & 1023, sl = l + t - PADT;
          v = ((unsigned)sl < 1024u) ? Ap[(size_t)(row + t - PADT)*lda + c] : 0.f;
        }
        As[kk][ml] = v;
      }
    }
    #pragma unroll
    for (int i = 0; i < (BK*BN)/256; ++i) {
      int e = tid + i*256;
      int nl = e % BN, kk = e / BN;
      Bs[kk][nl] = Bp[(size_t)(k0+kk)*N + n0 + nl];
    }
    __syncthreads();
    #pragma unroll
    for (int k = 0; k < BK; ++k) {
      float4 a0 = *(const float4*)&As[k][ty*4];
      float4 a1 = *(const float4*)&As[k][BM/2 + ty*4];
      float4 b0 = *(const float4*)&Bs[k][tx*4];
      float4 b1 = *(const float4*)&Bs[k][BN/2 + tx*4];
      float av[8] = {a0.x,a0.y,a0.z,a0.w,a1.x,a1.y,a1.z,a1.w};
      float bv[8] = {b0.x,b0.y,b0.z,b0.w,b1.x,b1.y,b1.z,b1.w};
      #pragma unroll
      for (int i = 0; i < 8; i++)
        #pragma unroll
        for (int j = 0; j < 8; j++) acc[i][j] += av[i]*bv[j];
    }
    __syncthreads();
  }
  float4 bias0 = *(const float4*)&biasp[n0 + tx*4];
  float4 bias1 = *(const float4*)&biasp[n0 + BN/2 + tx*4];
  float bn[8] = {bias0.x,bias0.y,bias0.z,bias0.w,bias1.x,bias1.y,bias1.z,bias1.w};
  #pragma unroll
  for (int i = 0; i < 8; i++) {
    int r = m0 + ((i < 4) ? (ty*4 + i) : (BM/2 + ty*4 + i - 4));
    float o[8];
    #pragma unroll
    for (int j = 0; j < 8; j++) {
      float v = acc[i][j] + bn[j];
      o[j] = RELU ? fmaxf(v, 0.f) : v;
    }
    *(float4*)&Cp[(size_t)r*N + n0 + tx*4] = make_float4(o[0],o[1],o[2],o[3]);
    *(float4*)&Cp[(size_t)r*N + n0 + BN/2 + tx*4] = make_float4(o[4],o[5],o[6],o[7]);
  }
}

// ---------------- LayerNorm + ReLU ----------------
__global__ __launch_bounds__(256)
void ln_relu_k(float* __restrict__ X, const float* __restrict__ g, const float* __restrict__ bt)
{
  const int lane = threadIdx.x & 63, wv = threadIdx.x >> 6;
  const size_t row = (size_t)blockIdx.x * 4 + wv;
  float4 v = *(const float4*)&X[row*256 + lane*4];
  float s = v.x + v.y + v.z + v.w;
  float q = v.x*v.x + v.y*v.y + v.z*v.z + v.w*v.w;
  #pragma unroll
  for (int d = 1; d < 64; d <<= 1) { s += __shfl_xor(s, d); q += __shfl_xor(q, d); }
  float mean = s * (1.f/256.f);
  float var = q * (1.f/256.f) - mean*mean;
  float inv = 1.f / sqrtf(var + 1e-5f);
  float4 gg = *(const float4*)&g[lane*4];
  float4 bb = *(const float4*)&bt[lane*4];
  float4 o;
  o.x = fmaxf(0.f, (v.x-mean)*inv*gg.x + bb.x);
  o.y = fmaxf(0.f, (v.y-mean)*inv*gg.y + bb.y);
  o.z = fmaxf(0.f, (v.z-mean)*inv*gg.z + bb.z);
  o.w = fmaxf(0.f, (v.w-mean)*inv*gg.w + bb.w);
  *(float4*)&X[row*256 + lane*4] = o;
}

// ---------------- fast activations (native exp2) ----------------
__device__ __forceinline__ float fast_sigmoid(float x){
  return 1.f / (1.f + exp2f(-x * L2E));
}
__device__ __forceinline__ float fast_tanh(float x){
  // 1 - 2/(exp2(2x*L2E)+1); saturates correctly at +/-inf
  return 1.f - 2.f / (exp2f(x * (2.f * L2E)) + 1.f);
}

// ---------------- LSTM recurrence: weights pinned in VGPRs, G prefetch ----------------
__global__ __launch_bounds__(512)
void lstm_k(const float* __restrict__ GF, const float* __restrict__ GB,
            const float* __restrict__ WhhF, const float* __restrict__ WhhB,
            float* __restrict__ Hcat)
{
  const int dir = blockIdx.y;
  const int b = blockIdx.x;
  const int j = threadIdx.x;
  const float* G = dir ? GB : GF;
  const float* Whh = dir ? WhhB : WhhF;
  float4 w4[32];
  #pragma unroll
  for (int i = 0; i < 32; ++i) w4[i] = *(const float4*)&Whh[(size_t)j*128 + i*4];
  __shared__ __align__(16) float hs[128];
  __shared__ float gs[512];
  if (j < 128) hs[j] = 0.f;
  float c = 0.f;
  const size_t gbase = (size_t)b * LL * 512 + j;
  float gcur = G[gbase + (size_t)(dir ? 1023 : 0) * 512];
  __syncthreads();
  for (int step = 0; step < LL; ++step) {
    const int l = dir ? (1023 - step) : step;
    // prefetch next step's gate input (consumed next iteration; hides latency)
    float gnext = 0.f;
    if (step + 1 < LL) {
      const int ln = dir ? (1022 - step) : (step + 1);
      gnext = G[gbase + (size_t)ln * 512];
    }
    // pin weights in VGPRs: forbid the compiler from sinking the loads into the loop
    #pragma unroll
    for (int i = 0; i < 32; ++i)
      asm volatile("" : "+v"(w4[i].x), "+v"(w4[i].y), "+v"(w4[i].z), "+v"(w4[i].w));
    float ac0 = gcur, ac1 = 0.f, ac2 = 0.f, ac3 = 0.f;
    #pragma unroll
    for (int i = 0; i < 32; i += 4) {
      float4 h0 = *(const float4*)&hs[4*i];
      float4 h1 = *(const float4*)&hs[4*i + 4];
      float4 h2 = *(const float4*)&hs[4*i + 8];
      float4 h3 = *(const float4*)&hs[4*i + 12];
      float4 x0 = w4[i], x1 = w4[i+1], x2 = w4[i+2], x3 = w4[i+3];
      ac0 += h0.x*x0.x + h0.y*x0.y + h0.z*x0.z + h0.w*x0.w;
      ac1 += h1.x*x1.x + h1.y*x1.y + h1.z*x1.z + h1.w*x1.w;
      ac2 += h2.x*x2.x + h2.y*x2.y + h2.z*x2.z + h2.w*x2.w;
      ac3 += h3.x*x3.x + h3.y*x3.y + h3.z*x3.z + h3.w*x3.w;
    }
    float acc = (ac0 + ac1) + (ac2 + ac3);
    float gv = ((j >> 7) == 2) ? fast_tanh(acc) : fast_sigmoid(acc);
    gs[j] = gv;
    __syncthreads();
    if (j < 128) {
      float ig = gs[j], fg = gs[128+j], g2 = gs[256+j], og = gs[384+j];
      c = fg*c + ig*g2;
      float hh = og * fast_tanh(c);
      hs[j] = hh;
      Hcat[((size_t)b*LL + l)*256 + (dir << 7) + j] = hh;
    }
    __syncthreads();
    gcur = gnext;
  }
}

// ---------------- wave helpers ----------------
__device__ __forceinline__ float wave_sum_f(float v){
  #pragma unroll
  for (int d = 1; d < 64; d <<= 1) v += __shfl_xor(v, d);
  return v;
}
__device__ __forceinline__ float wave_max_f(float v){
  #pragma unroll
  for (int d = 1; d < 64; d <<= 1) v = fmaxf(v, __shfl_xor(v, d));
  return v;
}
__device__ __forceinline__ float rdlanef(float v, int l){
  union { float f; int i; } u; u.f = v;
  u.i = __builtin_amdgcn_readlane(u.i, l);
  return u.f;
}
// fast lse2 via native exp2/log2
__device__ __forceinline__ float lse2f(float x, float y){
  float mx = fmaxf(x, y), mn = fminf(x, y);
  return mx + log2f(1.f + exp2f((mn - mx) * L2E)) * LN2;
}

// ---------------- emissions: wave per position ----------------
__global__ __launch_bounds__(256)
void emis_k(const float* __restrict__ F2, const float* __restrict__ W,
            const float* __restrict__ bias, float* __restrict__ EM)
{
  const int lane = threadIdx.x & 63;
  const size_t m = (size_t)blockIdx.x * 4 + (threadIdx.x >> 6);
  float f1 = F2[m*128 + lane], f2 = F2[m*128 + 64 + lane];
  float e0 = f1*W[lane*2]   + f2*W[(64+lane)*2];
  float e1 = f1*W[lane*2+1] + f2*W[(64+lane)*2+1];
  e0 = wave_sum_f(e0) + bias[0];
  e1 = wave_sum_f(e1) + bias[1];
  float* row = EM + m*SS;
  row[lane] = (lane == 0) ? e0 : e1;
  if (lane < 37) row[64 + lane] = e1;
}

// ---------------- CRF pass 1: forward (blocks 0-31) + Viterbi (blocks 32-63) ----------------
__global__ __launch_bounds__(64)
void crf1_k(const float* __restrict__ EM, const float* __restrict__ T,
            const float* __restrict__ startv, const float* __restrict__ endv,
            float* __restrict__ AL, float* __restrict__ LOGZ,
            float* __restrict__ paths, float* __restrict__ vbest)
{
  __shared__ unsigned int lptr[LL];
  const int lane = threadIdx.x;
  const int s1 = lane, s2 = 64 + lane;
  const bool has2 = lane < 37;
  float ta1, tb1 = 0.f, tc1 = NINF, ta2 = 0.f, tb2 = 0.f, tc2 = NINF;
  if (s1 == 0)      { ta1 = T[0]; tb1 = T[100*101 + 0]; }
  else if (s1 == 1) { ta1 = T[1]; tb1 = T[100*101 + 1]; }
  else ta1 = T[(s1-1)*101 + s1];
  if (s1 >= 4) tc1 = T[s1*101 + 100];
  if (has2) {
    if (s2 <= 98) ta2 = T[(s2-1)*101 + s2];
    else if (s2 == 99) { ta2 = T[98*101 + 99]; tb2 = T[99*101 + 99]; }
    if (s2 <= 99) tc2 = T[s2*101 + 100];
  }

  if (blockIdx.x < 32) {
    // ---------- forward ----------
    const int b = blockIdx.x;
    const float* E = EM + (size_t)b*LL*SS;
    float* A = AL + (size_t)b*LL*SS;
    float a1 = startv[s1] + E[s1];
    float a2 = has2 ? (startv[s2] + E[s2]) : NINF;
    A[s1] = a1;
    if (has2) A[s2] = a2;
    float M;
    {
      float v1 = a1 + tc1;
      float v2 = a2 + tc2;
      M = wave_max_f(fmaxf(v1, v2));
    }
    auto fstep = [&](int l, float e1, float e2) {
      float v1 = a1 + tc1;
      float v2 = a2 + tc2;
      float p = exp2f((v1 - M) * L2E) + exp2f((v2 - M) * L2E);
      p = fmaxf(wave_sum_f(p), 1e-37f);
      float lse100 = M + log2f(p) * LN2;
      float a1m1 = __shfl_up(a1, 1);
      float a2m1 = __shfl_up(a2, 1);
      float a1t  = rdlanef(a1, 63);
      float a0s  = rdlanef(a1, 0);
      float a100 = rdlanef(a2, 36);
      float n1 = (s1 <= 1) ? lse2f(a0s + ta1, a100 + tb1) : (a1m1 + ta1);
      float n2;
      if (s2 == 64) n2 = a1t + ta2;
      else if (s2 <= 98) n2 = a2m1 + ta2;
      else if (s2 == 99) n2 = lse2f(a2m1 + ta2, a2 + tb2);
      else n2 = lse100;
      a1 = n1 + e1;
      a2 = has2 ? (n2 + e2) : NINF;
      float* Ar = A + (size_t)l*SS;
      Ar[s1] = a1;
      if (has2) Ar[s2] = a2;
      M = lse100;
    };
    int l = 1;
    for (; l + 3 < LL; l += 4) {
      float e1a[4], e2a[4];
      #pragma unroll
      for (int u = 0; u < 4; ++u) {
        const float* e = E + (size_t)(l+u)*SS;
        e1a[u] = e[s1]; e2a[u] = has2 ? e[s2] : 0.f;
      }
      #pragma unroll
      for (int u = 0; u < 4; ++u) fstep(l+u, e1a[u], e2a[u]);
    }
    for (; l < LL; ++l) {
      const float* e = E + (size_t)l*SS;
      fstep(l, e[s1], has2 ? e[s2] : 0.f);
    }
    float w1 = a1 + ((s1 == 0) ? endv[0] : NEGV);
    float w2 = has2 ? (a2 + ((s2 == 100) ? endv[100] : NEGV)) : NINF;
    float Mx = wave_max_f(fmaxf(w1, w2));
    float P = wave_sum_f(exp2f((w1 - Mx) * L2E) + exp2f((w2 - Mx) * L2E));
    if (lane == 0) LOGZ[b] = Mx + log2f(P) * LN2;
  } else {
    // ---------- Viterbi ----------
    const int b = blockIdx.x - 32;
    const float* E = EM + (size_t)b*LL*SS;
    float v1 = startv[s1] + E[s1];
    float v2 = has2 ? (startv[s2] + E[s2]) : NINF;
    auto vstep = [&](int l, float e1, float e2) {
      float c1 = v1 + tc1;
      float c2 = v2 + tc2;
      float Mx = wave_max_f(fmaxf(c1, c2));
      unsigned long long m1 = __ballot(c1 == Mx);
      int bi;
      if (m1 != 0ULL) bi = __ffsll((unsigned long long)m1) - 1;
      else bi = 64 + __ffsll((unsigned long long)__ballot(c2 == Mx)) - 1;
      float v1m1 = __shfl_up(v1, 1);
      float v2m1 = __shfl_up(v2, 1);
      float v1t  = rdlanef(v1, 63);
      float v0s  = rdlanef(v1, 0);
      float v100 = rdlanef(v2, 36);
      float n1; int p1i;
      if (s1 <= 1) {
        float x0 = v0s + ta1, x1 = v100 + tb1;
        if (x1 > x0) { n1 = x1; p1i = 100; } else { n1 = x0; p1i = 0; }
      } else { n1 = v1m1 + ta1; p1i = s1 - 1; }
      float n2 = NINF; int p2i = 0;
      if (has2) {
        if (s2 == 64) { n2 = v1t + ta2; p2i = 63; }
        else if (s2 <= 98) { n2 = v2m1 + ta2; p2i = s2 - 1; }
        else if (s2 == 99) {
          float x98 = v2m1 + ta2, x99 = v2 + tb2;
          if (x99 > x98) { n2 = x99; p2i = 99; } else { n2 = x98; p2i = 98; }
        } else { n2 = Mx; p2i = bi; }
      }
      v1 = n1 + e1;
      v2 = has2 ? (n2 + e2) : NINF;
      int q0   = __builtin_amdgcn_readlane(p1i, 0);
      int q1   = __builtin_amdgcn_readlane(p1i, 1);
      int q99  = __builtin_amdgcn_readlane(p2i, 35);
      int q100 = __builtin_amdgcn_readlane(p2i, 36);
      if (lane == 0)
        lptr[l] = (unsigned)q0 | ((unsigned)q1 << 8) | ((unsigned)q99 << 16) | ((unsigned)q100 << 24);
    };
    int l = 1;
    for (; l + 3 < LL; l += 4) {
      float e1a[4], e2a[4];
      #pragma unroll
      for (int u = 0; u < 4; ++u) {
        const float* e = E + (size_t)(l+u)*SS;
        e1a[u] = e[s1]; e2a[u] = has2 ? e[s2] : 0.f;
      }
      #pragma unroll
      for (int u = 0; u < 4; ++u) vstep(l+u, e1a[u], e2a[u]);
    }
    for (; l < LL; ++l) {
      const float* e = E + (size_t)l*SS;
      vstep(l, e[s1], has2 ? e[s2] : 0.f);
    }
    float w1 = v1 + ((s1 == 0) ? endv[0] : NEGV);
    float w2 = has2 ? (v2 + ((s2 == 100) ? endv[100] : NEGV)) : NINF;
    float Mx = wave_max_f(fmaxf(w1, w2));
    unsigned long long m1 = __ballot(w1 == Mx);
    int last;
    if (m1 != 0ULL) last = __ffsll((unsigned long long)m1) - 1;
    else last = 64 + __ffsll((unsigned long long)__ballot(w2 == Mx)) - 1;
    if (lane == 0) vbest[b] = Mx;
    __syncthreads();
    float* po = paths + (size_t)b*LL;
    int st = last;
    for (int ch = 15; ch >= 0; --ch) {
      unsigned pk = lptr[ch*64 + lane];
      int myval = 0;
      #pragma unroll 1
      for (int j = 63; j >= 0; --j) {
        int t = ch*64 + j;
        if (t >= 1) {
          unsigned pp = __shfl((int)pk, j);
          int prev;
          if (st >= 2 && st <= 98) prev = st - 1;
          else if (st == 0)  prev = (int)(pp & 0xffu);
          else if (st == 1)  prev = (int)((pp >> 8) & 0xffu);
          else if (st == 99) prev = (int)((pp >> 16) & 0xffu);
          else               prev = (int)((pp >> 24) & 0xffu);
          if (j == lane) myval = prev;
          st = prev;
        }
      }
      int ii = ch*64 + lane;
      if (ii >= 1) po[ii - 1] = (float)myval;
    }
    if (lane == 0) po[1023] = (float)last;
  }
}

// ---------------- CRF pass 2: backward, write UNNORMALIZED alpha+beta ----------------
__global__ __launch_bounds__(64)
void crf_bwd_k(const float* __restrict__ EM, const float* __restrict__ AL,
               const float* __restrict__ T, const float* __restrict__ endv,
               float* __restrict__ U)
{
  const int b = blockIdx.x, lane = threadIdx.x;
  const int s1 = lane, s2 = 64 + lane;
  const bool has2 = lane < 37;
  const float* E = EM + (size_t)b*LL*SS;
  const float* A = AL + (size_t)b*LL*SS;
  float* PR = U + (size_t)b*LL*SS;
  float tn1 = T[s1*101 + s1 + 1];
  float tj1 = (s1 >= 4) ? T[s1*101 + 100] : 0.f;
  float tn2 = (has2 && s2 <= 99) ? T[s2*101 + s2 + 1] : 0.f;
  float tj2 = (has2 && s2 <= 98) ? T[s2*101 + 100] : 0.f;
  float t00 = T[0];
  float t9999 = T[99*101 + 99];
  float t100_0 = T[100*101 + 0], t100_1 = T[100*101 + 1];
  float b1 = (s1 == 0) ? endv[0] : NEGV;
  float b2 = has2 ? ((s2 == 100) ? endv[100] : NEGV) : NINF;
  PR[(size_t)1023*SS + s1] = A[(size_t)1023*SS + s1] + b1;
  if (has2) PR[(size_t)1023*SS + s2] = A[(size_t)1023*SS + s2] + b2;
  auto bstep = [&](int l, float e1, float e2, float a1r, float a2r) {
    float u1 = e1 + b1;
    float u2 = has2 ? (e2 + b2) : NINF;
    float un1 = __shfl_down(u1, 1);
    float un2 = __shfl_down(u2, 1);
    float u64v = rdlanef(u2, 0);
    float u99  = rdlanef(u2, 35);
    float u100 = rdlanef(u2, 36);
    float u0s  = rdlanef(u1, 0);
    float u1s  = rdlanef(u1, 1);
    float nb1;
    if (s1 == 0) nb1 = lse2f(t00 + u0s, tn1 + u1s);
    else if (s1 <= 3) nb1 = tn1 + un1;
    else if (s1 <= 62) nb1 = lse2f(tn1 + un1, tj1 + u100);
    else nb1 = lse2f(tn1 + u64v, tj1 + u100);
    float nb2 = NINF;
    if (has2) {
      if (s2 <= 98) nb2 = lse2f(tn2 + un2, tj2 + u100);
      else if (s2 == 99) nb2 = lse2f(t9999 + u99, tn2 + u100);
      else nb2 = lse2f(t100_0 + u0s, t100_1 + u1s);
    }
    b1 = nb1; b2 = has2 ? nb2 : NINF;
    PR[(size_t)(l-1)*SS + s1] = a1r + b1;
    if (has2) PR[(size_t)(l-1)*SS + s2] = a2r + b2;
  };
  int l = 1023;
  for (; l >= 4; l -= 4) {
    float e1a[4], e2a[4], a1a[4], a2a[4];
    #pragma unroll
    for (int u = 0; u < 4; ++u) {
      const float* e = E + (size_t)(l-u)*SS;
      const float* a = A + (size_t)(l-1-u)*SS;
      e1a[u] = e[s1]; e2a[u] = has2 ? e[s2] : 0.f;
      a1a[u] = a[s1]; a2a[u] = has2 ? a[s2] : 0.f;
    }
    #pragma unroll
    for (int u = 0; u < 4; ++u) bstep(l-u, e1a[u], e2a[u], a1a[u], a2a[u]);
  }
  for (; l >= 1; --l) {
    const float* e = E + (size_t)l*SS;
    const float* a = A + (size_t)(l-1)*SS;
    bstep(l, e[s1], has2 ? e[s2] : 0.f, a[s1], has2 ? a[s2] : 0.f);
  }
}

// ---------------- CRF pass 3: massively-parallel row softmax + pprobs ----------------
__global__ __launch_bounds__(256)
void crf_norm_k(float* __restrict__ PR, const float* __restrict__ vbest,
                const float* __restrict__ LOGZ, float* __restrict__ pprobs)
{
  const int lane = threadIdx.x & 63;
  const size_t m = (size_t)blockIdx.x * 4 + (threadIdx.x >> 6);
  float* row = PR + m*SS;
  float w1 = row[lane];
  float w2 = (lane < 37) ? row[64 + lane] : NINF;
  float M = wave_max_f(fmaxf(w1, w2));
  float p1 = exp2f((w1 - M) * L2E);
  float p2 = (lane < 37) ? exp2f((w2 - M) * L2E) : 0.f;
  float Z = wave_sum_f(p1 + p2);
  float rz = 1.f / Z;
  row[lane] = p1 * rz;
  if (lane < 37) row[64 + lane] = p2 * rz;
  if (blockIdx.x == 0 && threadIdx.x < 32)
    pprobs[threadIdx.x] = exp2f((vbest[threadIdx.x] - LOGZ[threadIdx.x]) * L2E);
}

extern "C" void kernel_launch(void* const* d_in, const int* in_sizes, int n_in,
                              void* d_out, int out_size, void* d_ws, size_t ws_size,
                              hipStream_t stream)
{
  (void)in_sizes; (void)n_in; (void)out_size; (void)ws_size;
  const float* emb      = (const float*)d_in[0];
  const float* W_bneck  = (const float*)d_in[3];
  const float* b_bneck  = (const float*)d_in[4];
  const float* ln_g     = (const float*)d_in[5];
  const float* ln_b     = (const float*)d_in[6];
  const float* conv1_w  = (const float*)d_in[7];
  const float* conv1_b  = (const float*)d_in[8];
  const float* Wih_f    = (const float*)d_in[9];
  const float* Whh_f    = (const float*)d_in[10];
  const float* bih_f    = (const float*)d_in[11];
  const float* bhh_f    = (const float*)d_in[12];
  const float* Wih_b    = (const float*)d_in[13];
  const float* Whh_b    = (const float*)d_in[14];
  const float* bih_b    = (const float*)d_in[15];
  const float* bhh_b    = (const float*)d_in[16];
  const float* conv2_w  = (const float*)d_in[17];
  const float* conv2_b  = (const float*)d_in[18];
  const float* W_emis   = (const float*)d_in[19];
  const float* b_emis   = (const float*)d_in[20];
  const float* crf_trans= (const float*)d_in[21];
  const float* crf_start= (const float*)d_in[22];
  const float* crf_end  = (const float*)d_in[23];
  float* ws = (float*)d_ws;
  float* out = (float*)d_out;

  dim3 b256(256);
  // 1. prep small tensors
  prep_k<<<dim3(7236), b256, 0, stream>>>(Wih_f, Wih_b, bih_f, bhh_f, bih_b, bhh_b,
                                          conv1_w, conv2_w, ws);
  // 2. bottleneck GEMM (transpose + PE fused), bias in epilogue
  gemm_tpl<64,256,0,0,false><<<dim3(512,1), b256, 0, stream>>>(
      nullptr, W_bneck, b_bneck, ws + OFF_X2, ws + OFF_PE, emb, 32768, 256, 1536, 0);
  // 3. LayerNorm + ReLU in-place
  ln_relu_k<<<dim3(8192), b256, 0, stream>>>(ws + OFF_X2, ln_g, ln_b);
  // 4. conv1 as im2col GEMM (K = 3*256), bias+relu
  gemm_tpl<256,64,2,1,true><<<dim3(128,1), b256, 0, stream>>>(
      ws + OFF_X2, ws + OFF_W1R, conv1_b, ws + OFF_X3, nullptr, nullptr, 32768, 64, 768, 256);
  // 5. LSTM input projections (both dirs)
  gemm_tpl<64,256,1,0,false><<<dim3(512,2), b256, 0, stream>>>(
      ws + OFF_X3, ws + OFF_WT_F, ws + OFF_BS_F, ws + OFF_GF, nullptr, nullptr, 32768, 512, 64, 64);
  gemm_tpl<64,256,1,0,false><<<dim3(512,2), b256, 0, stream>>>(
      ws + OFF_X3, ws + OFF_WT_B, ws + OFF_BS_B, ws + OFF_GB, nullptr, nullptr, 32768, 512, 64, 64);
  // 6. LSTM recurrence (fwd + bwd concurrently), writes Hcat over X2
  lstm_k<<<dim3(32,2), dim3(512), 0, stream>>>(ws + OFF_GF, ws + OFF_GB, Whh_f, Whh_b, ws + OFF_X2);
  // 7. conv2 as im2col GEMM (K = 5*256), bias+relu
  gemm_tpl<128,128,2,2,true><<<dim3(256,1), b256, 0, stream>>>(
      ws + OFF_X2, ws + OFF_W2R, conv2_b, ws + OFF_F2, nullptr, nullptr, 32768, 128, 1280, 256);
  // 8. emissions + repeat to 101 states
  emis_k<<<dim3(8192), b256, 0, stream>>>(ws + OFF_F2, W_emis, b_emis, ws + OFF_EMIS);
  // 9. CRF pass 1: forward (blocks 0-31) + Viterbi+backtrace (blocks 32-63), concurrent
  crf1_k<<<dim3(64), dim3(64), 0, stream>>>(ws + OFF_EMIS, crf_trans, crf_start, crf_end,
                                            ws + OFF_ALPHA, ws + OFF_LOGZ,
                                            out + 3309568, ws + OFF_VBEST);
  // 10. CRF pass 2: backward, unnormalized alpha+beta into probs area
  crf_bwd_k<<<dim3(32), dim3(64), 0, stream>>>(ws + OFF_EMIS, ws + OFF_ALPHA,
                                               crf_trans, crf_end, out);
  // 11. CRF pass 3: row softmax + path probs
  crf_norm_k<<<dim3(8192), b256, 0, stream>>>(out, ws + OFF_VBEST, ws + OFF_LOGZ,
                                              out + 3342336);
}

// Round 4
// 3172.374 us; speedup vs baseline: 2.2383x; 1.0027x over previous
//
#include <hip/hip_runtime.h>
#include <cstdint>
#include <cstddef>

// Problem constants
#define BB 32
#define LL 1024
#define DD 1536
#define SS 101
#define NEGV (-1e4f)
#define NINF (-1e30f)
#define L2E 1.4426950408889634f
#define LN2 0.6931471805599453f

// workspace layout (float offsets)
#define NPE   (1024*1536)
#define NX2   (32768*256)
#define NX3   (32768*64)
#define NG    (32768*512)
#define NF2   (32768*128)
#define NEM   (32768*101)

#define OFF_PE    0
#define OFF_X2    (OFF_PE + NPE)        // Y1 -> X2 (in-place LN) -> later Hcat
#define OFF_X3    (OFF_X2 + NX2)
#define OFF_GF    (OFF_X3 + NX3)
#define OFF_GB    (OFF_GF + NG)
#define OFF_F2    (OFF_GF)              // reuse GF after LSTM
#define OFF_EMIS  (OFF_GF + NF2)
#define OFF_ALPHA (OFF_EMIS + NEM)
#define OFF_LOGZ  (OFF_ALPHA + NEM)
#define OFF_VBEST (OFF_LOGZ + 64)
#define OFF_WT_F  (OFF_GB + NG)
#define OFF_WT_B  (OFF_WT_F + 32768)
#define OFF_BS_F  (OFF_WT_B + 32768)
#define OFF_BS_B  (OFF_BS_F + 512)
#define OFF_W1R   (OFF_BS_B + 512)
#define OFF_W2R   (OFF_W1R + 49152)

// LDS-only barrier: make LDS writes visible + sync, WITHOUT draining vmcnt
// (global prefetch/stores stay in flight across the barrier).
#define LDS_BARRIER asm volatile("s_waitcnt lgkmcnt(0)\ns_barrier" ::: "memory")

// ---------------- prep: PE (transposed [k][l]), Wih^T, bias sums, conv weights rearranged t-major ----------------
__global__ __launch_bounds__(256)
void prep_k(const float* __restrict__ Wihf, const float* __restrict__ Wihb,
            const float* __restrict__ bihf, const float* __restrict__ bhhf,
            const float* __restrict__ bihb, const float* __restrict__ bhhb,
            const float* __restrict__ w1, const float* __restrict__ w2,
            float* __restrict__ ws)
{
  int idx = blockIdx.x * 256 + threadIdx.x;
  if (idx < NPE) {
    int k = idx >> 10, l = idx & 1023;
    int j2 = (k >> 1) * 2;
    float freq = expf((float)j2 * (-9.210340371976184f / 1536.f));
    float ang = (float)l * freq;
    ws[OFF_PE + idx] = (k & 1) ? cosf(ang) : sinf(ang);
    return;
  }
  idx -= NPE;
  if (idx < 32768) { int k = idx >> 9, n = idx & 511; ws[OFF_WT_F + idx] = Wihf[n*64 + k]; return; }
  idx -= 32768;
  if (idx < 32768) { int k = idx >> 9, n = idx & 511; ws[OFF_WT_B + idx] = Wihb[n*64 + k]; return; }
  idx -= 32768;
  if (idx < 512) { ws[OFF_BS_F + idx] = bihf[idx] + bhhf[idx]; return; }
  idx -= 512;
  if (idx < 512) { ws[OFF_BS_B + idx] = bihb[idx] + bhhb[idx]; return; }
  idx -= 512;
  if (idx < 49152) {  // w1r[(t*256+c)*64+f] = w1[f][c][t]
    int f = idx & 63, tc = idx >> 6;
    int t = tc >> 8, c = tc & 255;
    ws[OFF_W1R + idx] = w1[(f*256 + c)*3 + t];
    return;
  }
  idx -= 49152;
  if (idx < 163840) { // w2r[(t*256+c)*128+f] = w2[f][c][t]
    int f = idx & 127, tc = idx >> 7;
    int t = tc >> 8, c = tc & 255;
    ws[OFF_W2R + idx] = w2[(f*256 + c)*5 + t];
  }
}

// ---------------- generic fp32 tiled GEMM ----------------
template<int BM, int BN, int AMODE, int PADT, bool RELU>
__global__ __launch_bounds__(256)
void gemm_tpl(const float* __restrict__ Ap, const float* __restrict__ Bp,
              const float* __restrict__ biasp, float* __restrict__ Cp,
              const float* __restrict__ PEp, const float* __restrict__ EMBp,
              int M, int N, int K, int lda)
{
  constexpr int BK = 16;
  __shared__ __align__(16) float As[BK][BM + 4];
  __shared__ __align__(16) float Bs[BK][BN];
  constexpr int TX = BN / 8, TY = BM / 8;
  const int tid = threadIdx.x;
  const int tx = tid % TX, ty = tid / TX;
  const int m0 = blockIdx.x * BM;
  const int n0 = blockIdx.y * BN;
  float acc[8][8];
  #pragma unroll
  for (int i = 0; i < 8; i++)
    #pragma unroll
    for (int j = 0; j < 8; j++) acc[i][j] = 0.f;

  for (int k0 = 0; k0 < K; k0 += BK) {
    if constexpr (AMODE == 0) {
      #pragma unroll
      for (int i = 0; i < (BK*BM)/256; ++i) {
        int e = tid + i*256;
        int ml = e % BM, kk = e / BM;
        int row = m0 + ml; int b = row >> 10; int l = row & 1023;
        int k = k0 + kk;
        As[kk][ml] = EMBp[((size_t)b*DD + k)*LL + l] + PEp[(size_t)k*LL + l];
      }
    } else {
      #pragma unroll
      for (int i = 0; i < (BK*BM)/256; ++i) {
        int e = tid + i*256;
        int kk = e % BK, ml = e / BK;
        int row = m0 + ml; int k = k0 + kk;
        float v;
        if constexpr (AMODE == 1) {
          v = Ap[(size_t)row*lda + k];
        } else {
          int c = k & 255, t = k >> 8;
          int l = row & 1023, sl = l + t - PADT;
          v = ((unsigned)sl < 1024u) ? Ap[(size_t)(row + t - PADT)*lda + c] : 0.f;
        }
        As[kk][ml] = v;
      }
    }
    #pragma unroll
    for (int i = 0; i < (BK*BN)/256; ++i) {
      int e = tid + i*256;
      int nl = e % BN, kk = e / BN;
      Bs[kk][nl] = Bp[(size_t)(k0+kk)*N + n0 + nl];
    }
    __syncthreads();
    #pragma unroll
    for (int k = 0; k < BK; ++k) {
      float4 a0 = *(const float4*)&As[k][ty*4];
      float4 a1 = *(const float4*)&As[k][BM/2 + ty*4];
      float4 b0 = *(const float4*)&Bs[k][tx*4];
      float4 b1 = *(const float4*)&Bs[k][BN/2 + tx*4];
      float av[8] = {a0.x,a0.y,a0.z,a0.w,a1.x,a1.y,a1.z,a1.w};
      float bv[8] = {b0.x,b0.y,b0.z,b0.w,b1.x,b1.y,b1.z,b1.w};
      #pragma unroll
      for (int i = 0; i < 8; i++)
        #pragma unroll
        for (int j = 0; j < 8; j++) acc[i][j] += av[i]*bv[j];
    }
    __syncthreads();
  }
  float4 bias0 = *(const float4*)&biasp[n0 + tx*4];
  float4 bias1 = *(const float4*)&biasp[n0 + BN/2 + tx*4];
  float bn[8] = {bias0.x,bias0.y,bias0.z,bias0.w,bias1.x,bias1.y,bias1.z,bias1.w};
  #pragma unroll
  for (int i = 0; i < 8; i++) {
    int r = m0 + ((i < 4) ? (ty*4 + i) : (BM/2 + ty*4 + i - 4));
    float o[8];
    #pragma unroll
    for (int j = 0; j < 8; j++) {
      float v = acc[i][j] + bn[j];
      o[j] = RELU ? fmaxf(v, 0.f) : v;
    }
    *(float4*)&Cp[(size_t)r*N + n0 + tx*4] = make_float4(o[0],o[1],o[2],o[3]);
    *(float4*)&Cp[(size_t)r*N + n0 + BN/2 + tx*4] = make_float4(o[4],o[5],o[6],o[7]);
  }
}

// ---------------- LayerNorm + ReLU ----------------
__global__ __launch_bounds__(256)
void ln_relu_k(float* __restrict__ X, const float* __restrict__ g, const float* __restrict__ bt)
{
  const int lane = threadIdx.x & 63, wv = threadIdx.x >> 6;
  const size_t row = (size_t)blockIdx.x * 4 + wv;
  float4 v = *(const float4*)&X[row*256 + lane*4];
  float s = v.x + v.y + v.z + v.w;
  float q = v.x*v.x + v.y*v.y + v.z*v.z + v.w*v.w;
  #pragma unroll
  for (int d = 1; d < 64; d <<= 1) { s += __shfl_xor(s, d); q += __shfl_xor(q, d); }
  float mean = s * (1.f/256.f);
  float var = q * (1.f/256.f) - mean*mean;
  float inv = 1.f / sqrtf(var + 1e-5f);
  float4 gg = *(const float4*)&g[lane*4];
  float4 bb = *(const float4*)&bt[lane*4];
  float4 o;
  o.x = fmaxf(0.f, (v.x-mean)*inv*gg.x + bb.x);
  o.y = fmaxf(0.f, (v.y-mean)*inv*gg.y + bb.y);
  o.z = fmaxf(0.f, (v.z-mean)*inv*gg.z + bb.z);
  o.w = fmaxf(0.f, (v.w-mean)*inv*gg.w + bb.w);
  *(float4*)&X[row*256 + lane*4] = o;
}

// ---------------- fast activations (native exp2) ----------------
__device__ __forceinline__ float fast_sigmoid(float x){
  return 1.f / (1.f + exp2f(-x * L2E));
}
__device__ __forceinline__ float fast_tanh(float x){
  return 1.f - 2.f / (exp2f(x * (2.f * L2E)) + 1.f);
}

// ---------------- LSTM recurrence: weights truly pinned in VGPRs, LDS-only barriers ----------------
__global__ __launch_bounds__(512)
void lstm_k(const float* __restrict__ GF, const float* __restrict__ GB,
            const float* __restrict__ WhhF, const float* __restrict__ WhhB,
            float* __restrict__ Hcat)
{
  const int dir = blockIdx.y;
  const int b = blockIdx.x;
  const int j = threadIdx.x;
  const float* G = dir ? GB : GF;
  const float* Whh = dir ? WhhB : WhhF;
  // scalar array + component-wise fill (SROA-friendly) -> true register residency
  float w[128];
  #pragma unroll
  for (int i = 0; i < 32; ++i) {
    float4 t4 = *(const float4*)&Whh[(size_t)j*128 + i*4];
    w[4*i+0] = t4.x; w[4*i+1] = t4.y; w[4*i+2] = t4.z; w[4*i+3] = t4.w;
  }
  __shared__ __align__(16) float hs[128];
  __shared__ float gs[512];
  if (j < 128) hs[j] = 0.f;
  float c = 0.f;
  const size_t gbase = (size_t)b * LL * 512 + j;
  float gcur = G[gbase + (size_t)(dir ? 1023 : 0) * 512];
  __syncthreads();
  for (int step = 0; step < LL; ++step) {
    const int l = dir ? (1023 - step) : step;
    // prefetch next step's gate input (stays in flight across the LDS barriers)
    float gnext = 0.f;
    if (step + 1 < LL) {
      const int ln = dir ? (1022 - step) : (step + 1);
      gnext = G[gbase + (size_t)ln * 512];
    }
    // loop-carried register pin: the "+v" output feeds next iteration's input,
    // so the compiler cannot re-load these from memory.
    #pragma unroll
    for (int k = 0; k < 128; ++k)
      asm volatile("" : "+v"(w[k]));
    float ac0 = gcur, ac1 = 0.f, ac2 = 0.f, ac3 = 0.f;
    #pragma unroll
    for (int i = 0; i < 8; ++i) {
      float4 h0 = *(const float4*)&hs[16*i];
      float4 h1 = *(const float4*)&hs[16*i + 4];
      float4 h2 = *(const float4*)&hs[16*i + 8];
      float4 h3 = *(const float4*)&hs[16*i + 12];
      ac0 += h0.x*w[16*i]    + h0.y*w[16*i+1]  + h0.z*w[16*i+2]  + h0.w*w[16*i+3];
      ac1 += h1.x*w[16*i+4]  + h1.y*w[16*i+5]  + h1.z*w[16*i+6]  + h1.w*w[16*i+7];
      ac2 += h2.x*w[16*i+8]  + h2.y*w[16*i+9]  + h2.z*w[16*i+10] + h2.w*w[16*i+11];
      ac3 += h3.x*w[16*i+12] + h3.y*w[16*i+13] + h3.z*w[16*i+14] + h3.w*w[16*i+15];
    }
    float acc = (ac0 + ac1) + (ac2 + ac3);
    float gv = ((j >> 7) == 2) ? fast_tanh(acc) : fast_sigmoid(acc);
    gs[j] = gv;
    LDS_BARRIER;
    if (j < 128) {
      float ig = gs[j], fg = gs[128+j], g2 = gs[256+j], og = gs[384+j];
      c = fg*c + ig*g2;
      float hh = og * fast_tanh(c);
      hs[j] = hh;
      Hcat[((size_t)b*LL + l)*256 + (dir << 7) + j] = hh;
    }
    LDS_BARRIER;
    gcur = gnext;
  }
}

// ---------------- wave helpers ----------------
__device__ __forceinline__ float wave_sum_f(float v){
  #pragma unroll
  for (int d = 1; d < 64; d <<= 1) v += __shfl_xor(v, d);
  return v;
}
__device__ __forceinline__ float wave_max_f(float v){
  #pragma unroll
  for (int d = 1; d < 64; d <<= 1) v = fmaxf(v, __shfl_xor(v, d));
  return v;
}
__device__ __forceinline__ float rdlanef(float v, int l){
  union { float f; int i; } u; u.f = v;
  u.i = __builtin_amdgcn_readlane(u.i, l);
  return u.f;
}
// fast lse2 via native exp2/log2
__device__ __forceinline__ float lse2f(float x, float y){
  float mx = fmaxf(x, y), mn = fminf(x, y);
  return mx + log2f(1.f + exp2f((mn - mx) * L2E)) * LN2;
}

// ---------------- emissions: wave per position ----------------
__global__ __launch_bounds__(256)
void emis_k(const float* __restrict__ F2, const float* __restrict__ W,
            const float* __restrict__ bias, float* __restrict__ EM)
{
  const int lane = threadIdx.x & 63;
  const size_t m = (size_t)blockIdx.x * 4 + (threadIdx.x >> 6);
  float f1 = F2[m*128 + lane], f2 = F2[m*128 + 64 + lane];
  float e0 = f1*W[lane*2]   + f2*W[(64+lane)*2];
  float e1 = f1*W[lane*2+1] + f2*W[(64+lane)*2+1];
  e0 = wave_sum_f(e0) + bias[0];
  e1 = wave_sum_f(e1) + bias[1];
  float* row = EM + m*SS;
  row[lane] = (lane == 0) ? e0 : e1;
  if (lane < 37) row[64 + lane] = e1;
}

// ---------------- CRF pass 1: forward (blocks 0-31) + Viterbi (blocks 32-63) ----------------
__global__ __launch_bounds__(64)
void crf1_k(const float* __restrict__ EM, const float* __restrict__ T,
            const float* __restrict__ startv, const float* __restrict__ endv,
            float* __restrict__ AL, float* __restrict__ LOGZ,
            float* __restrict__ paths, float* __restrict__ vbest)
{
  __shared__ unsigned int lptr[LL];
  const int lane = threadIdx.x;
  const int s1 = lane, s2 = 64 + lane;
  const bool has2 = lane < 37;
  float ta1, tb1 = 0.f, tc1 = NINF, ta2 = 0.f, tb2 = 0.f, tc2 = NINF;
  if (s1 == 0)      { ta1 = T[0]; tb1 = T[100*101 + 0]; }
  else if (s1 == 1) { ta1 = T[1]; tb1 = T[100*101 + 1]; }
  else ta1 = T[(s1-1)*101 + s1];
  if (s1 >= 4) tc1 = T[s1*101 + 100];
  if (has2) {
    if (s2 <= 98) ta2 = T[(s2-1)*101 + s2];
    else if (s2 == 99) { ta2 = T[98*101 + 99]; tb2 = T[99*101 + 99]; }
    if (s2 <= 99) tc2 = T[s2*101 + 100];
  }

  if (blockIdx.x < 32) {
    // ---------- forward ----------
    const int b = blockIdx.x;
    const float* E = EM + (size_t)b*LL*SS;
    float* A = AL + (size_t)b*LL*SS;
    float a1 = startv[s1] + E[s1];
    float a2 = has2 ? (startv[s2] + E[s2]) : NINF;
    A[s1] = a1;
    if (has2) A[s2] = a2;
    float M;
    {
      float v1 = a1 + tc1;
      float v2 = a2 + tc2;
      M = wave_max_f(fmaxf(v1, v2));
    }
    auto fstep = [&](int l, float e1, float e2) {
      float v1 = a1 + tc1;
      float v2 = a2 + tc2;
      float p = exp2f((v1 - M) * L2E) + exp2f((v2 - M) * L2E);
      p = fmaxf(wave_sum_f(p), 1e-37f);
      float lse100 = M + log2f(p) * LN2;
      float a1m1 = __shfl_up(a1, 1);
      float a2m1 = __shfl_up(a2, 1);
      float a1t  = rdlanef(a1, 63);
      float a0s  = rdlanef(a1, 0);
      float a100 = rdlanef(a2, 36);
      float n1 = (s1 <= 1) ? lse2f(a0s + ta1, a100 + tb1) : (a1m1 + ta1);
      float n2;
      if (s2 == 64) n2 = a1t + ta2;
      else if (s2 <= 98) n2 = a2m1 + ta2;
      else if (s2 == 99) n2 = lse2f(a2m1 + ta2, a2 + tb2);
      else n2 = lse100;
      a1 = n1 + e1;
      a2 = has2 ? (n2 + e2) : NINF;
      float* Ar = A + (size_t)l*SS;
      Ar[s1] = a1;
      if (has2) Ar[s2] = a2;
      M = lse100;
    };
    int l = 1;
    for (; l + 3 < LL; l += 4) {
      float e1a[4], e2a[4];
      #pragma unroll
      for (int u = 0; u < 4; ++u) {
        const float* e = E + (size_t)(l+u)*SS;
        e1a[u] = e[s1]; e2a[u] = has2 ? e[s2] : 0.f;
      }
      #pragma unroll
      for (int u = 0; u < 4; ++u) fstep(l+u, e1a[u], e2a[u]);
    }
    for (; l < LL; ++l) {
      const float* e = E + (size_t)l*SS;
      fstep(l, e[s1], has2 ? e[s2] : 0.f);
    }
    float w1 = a1 + ((s1 == 0) ? endv[0] : NEGV);
    float w2 = has2 ? (a2 + ((s2 == 100) ? endv[100] : NEGV)) : NINF;
    float Mx = wave_max_f(fmaxf(w1, w2));
    float P = wave_sum_f(exp2f((w1 - Mx) * L2E) + exp2f((w2 - Mx) * L2E));
    if (lane == 0) LOGZ[b] = Mx + log2f(P) * LN2;
  } else {
    // ---------- Viterbi ----------
    const int b = blockIdx.x - 32;
    const float* E = EM + (size_t)b*LL*SS;
    float v1 = startv[s1] + E[s1];
    float v2 = has2 ? (startv[s2] + E[s2]) : NINF;
    auto vstep = [&](int l, float e1, float e2) {
      float c1 = v1 + tc1;
      float c2 = v2 + tc2;
      float Mx = wave_max_f(fmaxf(c1, c2));
      unsigned long long m1 = __ballot(c1 == Mx);
      int bi;
      if (m1 != 0ULL) bi = __ffsll((unsigned long long)m1) - 1;
      else bi = 64 + __ffsll((unsigned long long)__ballot(c2 == Mx)) - 1;
      float v1m1 = __shfl_up(v1, 1);
      float v2m1 = __shfl_up(v2, 1);
      float v1t  = rdlanef(v1, 63);
      float v0s  = rdlanef(v1, 0);
      float v100 = rdlanef(v2, 36);
      float n1; int p1i;
      if (s1 <= 1) {
        float x0 = v0s + ta1, x1 = v100 + tb1;
        if (x1 > x0) { n1 = x1; p1i = 100; } else { n1 = x0; p1i = 0; }
      } else { n1 = v1m1 + ta1; p1i = s1 - 1; }
      float n2 = NINF; int p2i = 0;
      if (has2) {
        if (s2 == 64) { n2 = v1t + ta2; p2i = 63; }
        else if (s2 <= 98) { n2 = v2m1 + ta2; p2i = s2 - 1; }
        else if (s2 == 99) {
          float x98 = v2m1 + ta2, x99 = v2 + tb2;
          if (x99 > x98) { n2 = x99; p2i = 99; } else { n2 = x98; p2i = 98; }
        } else { n2 = Mx; p2i = bi; }
      }
      v1 = n1 + e1;
      v2 = has2 ? (n2 + e2) : NINF;
      int q0   = __builtin_amdgcn_readlane(p1i, 0);
      int q1   = __builtin_amdgcn_readlane(p1i, 1);
      int q99  = __builtin_amdgcn_readlane(p2i, 35);
      int q100 = __builtin_amdgcn_readlane(p2i, 36);
      if (lane == 0)
        lptr[l] = (unsigned)q0 | ((unsigned)q1 << 8) | ((unsigned)q99 << 16) | ((unsigned)q100 << 24);
    };
    int l = 1;
    for (; l + 3 < LL; l += 4) {
      float e1a[4], e2a[4];
      #pragma unroll
      for (int u = 0; u < 4; ++u) {
        const float* e = E + (size_t)(l+u)*SS;
        e1a[u] = e[s1]; e2a[u] = has2 ? e[s2] : 0.f;
      }
      #pragma unroll
      for (int u = 0; u < 4; ++u) vstep(l+u, e1a[u], e2a[u]);
    }
    for (; l < LL; ++l) {
      const float* e = E + (size_t)l*SS;
      vstep(l, e[s1], has2 ? e[s2] : 0.f);
    }
    float w1 = v1 + ((s1 == 0) ? endv[0] : NEGV);
    float w2 = has2 ? (v2 + ((s2 == 100) ? endv[100] : NEGV)) : NINF;
    float Mx = wave_max_f(fmaxf(w1, w2));
    unsigned long long m1 = __ballot(w1 == Mx);
    int last;
    if (m1 != 0ULL) last = __ffsll((unsigned long long)m1) - 1;
    else last = 64 + __ffsll((unsigned long long)__ballot(w2 == Mx)) - 1;
    if (lane == 0) vbest[b] = Mx;
    __syncthreads();
    float* po = paths + (size_t)b*LL;
    int st = last;
    for (int ch = 15; ch >= 0; --ch) {
      unsigned pk = lptr[ch*64 + lane];
      int myval = 0;
      #pragma unroll 1
      for (int j = 63; j >= 0; --j) {
        int t = ch*64 + j;
        if (t >= 1) {
          unsigned pp = __shfl((int)pk, j);
          int prev;
          if (st >= 2 && st <= 98) prev = st - 1;
          else if (st == 0)  prev = (int)(pp & 0xffu);
          else if (st == 1)  prev = (int)((pp >> 8) & 0xffu);
          else if (st == 99) prev = (int)((pp >> 16) & 0xffu);
          else               prev = (int)((pp >> 24) & 0xffu);
          if (j == lane) myval = prev;
          st = prev;
        }
      }
      int ii = ch*64 + lane;
      if (ii >= 1) po[ii - 1] = (float)myval;
    }
    if (lane == 0) po[1023] = (float)last;
  }
}

// ---------------- CRF pass 2: backward, write UNNORMALIZED alpha+beta ----------------
__global__ __launch_bounds__(64)
void crf_bwd_k(const float* __restrict__ EM, const float* __restrict__ AL,
               const float* __restrict__ T, const float* __restrict__ endv,
               float* __restrict__ U)
{
  const int b = blockIdx.x, lane = threadIdx.x;
  const int s1 = lane, s2 = 64 + lane;
  const bool has2 = lane < 37;
  const float* E = EM + (size_t)b*LL*SS;
  const float* A = AL + (size_t)b*LL*SS;
  float* PR = U + (size_t)b*LL*SS;
  float tn1 = T[s1*101 + s1 + 1];
  float tj1 = (s1 >= 4) ? T[s1*101 + 100] : 0.f;
  float tn2 = (has2 && s2 <= 99) ? T[s2*101 + s2 + 1] : 0.f;
  float tj2 = (has2 && s2 <= 98) ? T[s2*101 + 100] : 0.f;
  float t00 = T[0];
  float t9999 = T[99*101 + 99];
  float t100_0 = T[100*101 + 0], t100_1 = T[100*101 + 1];
  float b1 = (s1 == 0) ? endv[0] : NEGV;
  float b2 = has2 ? ((s2 == 100) ? endv[100] : NEGV) : NINF;
  PR[(size_t)1023*SS + s1] = A[(size_t)1023*SS + s1] + b1;
  if (has2) PR[(size_t)1023*SS + s2] = A[(size_t)1023*SS + s2] + b2;
  auto bstep = [&](int l, float e1, float e2, float a1r, float a2r) {
    float u1 = e1 + b1;
    float u2 = has2 ? (e2 + b2) : NINF;
    float un1 = __shfl_down(u1, 1);
    float un2 = __shfl_down(u2, 1);
    float u64v = rdlanef(u2, 0);
    float u99  = rdlanef(u2, 35);
    float u100 = rdlanef(u2, 36);
    float u0s  = rdlanef(u1, 0);
    float u1s  = rdlanef(u1, 1);
    float nb1;
    if (s1 == 0) nb1 = lse2f(t00 + u0s, tn1 + u1s);
    else if (s1 <= 3) nb1 = tn1 + un1;
    else if (s1 <= 62) nb1 = lse2f(tn1 + un1, tj1 + u100);
    else nb1 = lse2f(tn1 + u64v, tj1 + u100);
    float nb2 = NINF;
    if (has2) {
      if (s2 <= 98) nb2 = lse2f(tn2 + un2, tj2 + u100);
      else if (s2 == 99) nb2 = lse2f(t9999 + u99, tn2 + u100);
      else nb2 = lse2f(t100_0 + u0s, t100_1 + u1s);
    }
    b1 = nb1; b2 = has2 ? nb2 : NINF;
    PR[(size_t)(l-1)*SS + s1] = a1r + b1;
    if (has2) PR[(size_t)(l-1)*SS + s2] = a2r + b2;
  };
  int l = 1023;
  for (; l >= 4; l -= 4) {
    float e1a[4], e2a[4], a1a[4], a2a[4];
    #pragma unroll
    for (int u = 0; u < 4; ++u) {
      const float* e = E + (size_t)(l-u)*SS;
      const float* a = A + (size_t)(l-1-u)*SS;
      e1a[u] = e[s1]; e2a[u] = has2 ? e[s2] : 0.f;
      a1a[u] = a[s1]; a2a[u] = has2 ? a[s2] : 0.f;
    }
    #pragma unroll
    for (int u = 0; u < 4; ++u) bstep(l-u, e1a[u], e2a[u], a1a[u], a2a[u]);
  }
  for (; l >= 1; --l) {
    const float* e = E + (size_t)l*SS;
    const float* a = A + (size_t)(l-1)*SS;
    bstep(l, e[s1], has2 ? e[s2] : 0.f, a[s1], has2 ? a[s2] : 0.f);
  }
}

// ---------------- CRF pass 3: massively-parallel row softmax + pprobs ----------------
__global__ __launch_bounds__(256)
void crf_norm_k(float* __restrict__ PR, const float* __restrict__ vbest,
                const float* __restrict__ LOGZ, float* __restrict__ pprobs)
{
  const int lane = threadIdx.x & 63;
  const size_t m = (size_t)blockIdx.x * 4 + (threadIdx.x >> 6);
  float* row = PR + m*SS;
  float w1 = row[lane];
  float w2 = (lane < 37) ? row[64 + lane] : NINF;
  float M = wave_max_f(fmaxf(w1, w2));
  float p1 = exp2f((w1 - M) * L2E);
  float p2 = (lane < 37) ? exp2f((w2 - M) * L2E) : 0.f;
  float Z = wave_sum_f(p1 + p2);
  float rz = 1.f / Z;
  row[lane] = p1 * rz;
  if (lane < 37) row[64 + lane] = p2 * rz;
  if (blockIdx.x == 0 && threadIdx.x < 32)
    pprobs[threadIdx.x] = exp2f((vbest[threadIdx.x] - LOGZ[threadIdx.x]) * L2E);
}

extern "C" void kernel_launch(void* const* d_in, const int* in_sizes, int n_in,
                              void* d_out, int out_size, void* d_ws, size_t ws_size,
                              hipStream_t stream)
{
  (void)in_sizes; (void)n_in; (void)out_size; (void)ws_size;
  const float* emb      = (const float*)d_in[0];
  const float* W_bneck  = (const float*)d_in[3];
  const float* b_bneck  = (const float*)d_in[4];
  const float* ln_g     = (const float*)d_in[5];
  const float* ln_b     = (const float*)d_in[6];
  const float* conv1_w  = (const float*)d_in[7];
  const float* conv1_b  = (const float*)d_in[8];
  const float* Wih_f    = (const float*)d_in[9];
  const float* Whh_f    = (const float*)d_in[10];
  const float* bih_f    = (const float*)d_in[11];
  const float* bhh_f    = (const float*)d_in[12];
  const float* Wih_b    = (const float*)d_in[13];
  const float* Whh_b    = (const float*)d_in[14];
  const float* bih_b    = (const float*)d_in[15];
  const float* bhh_b    = (const float*)d_in[16];
  const float* conv2_w  = (const float*)d_in[17];
  const float* conv2_b  = (const float*)d_in[18];
  const float* W_emis   = (const float*)d_in[19];
  const float* b_emis   = (const float*)d_in[20];
  const float* crf_trans= (const float*)d_in[21];
  const float* crf_start= (const float*)d_in[22];
  const float* crf_end  = (const float*)d_in[23];
  float* ws = (float*)d_ws;
  float* out = (float*)d_out;

  dim3 b256(256);
  // 1. prep small tensors
  prep_k<<<dim3(7236), b256, 0, stream>>>(Wih_f, Wih_b, bih_f, bhh_f, bih_b, bhh_b,
                                          conv1_w, conv2_w, ws);
  // 2. bottleneck GEMM (transpose + PE fused), bias in epilogue
  gemm_tpl<64,256,0,0,false><<<dim3(512,1), b256, 0, stream>>>(
      nullptr, W_bneck, b_bneck, ws + OFF_X2, ws + OFF_PE, emb, 32768, 256, 1536, 0);
  // 3. LayerNorm + ReLU in-place
  ln_relu_k<<<dim3(8192), b256, 0, stream>>>(ws + OFF_X2, ln_g, ln_b);
  // 4. conv1 as im2col GEMM (K = 3*256), bias+relu
  gemm_tpl<256,64,2,1,true><<<dim3(128,1), b256, 0, stream>>>(
      ws + OFF_X2, ws + OFF_W1R, conv1_b, ws + OFF_X3, nullptr, nullptr, 32768, 64, 768, 256);
  // 5. LSTM input projections (both dirs)
  gemm_tpl<64,256,1,0,false><<<dim3(512,2), b256, 0, stream>>>(
      ws + OFF_X3, ws + OFF_WT_F, ws + OFF_BS_F, ws + OFF_GF, nullptr, nullptr, 32768, 512, 64, 64);
  gemm_tpl<64,256,1,0,false><<<dim3(512,2), b256, 0, stream>>>(
      ws + OFF_X3, ws + OFF_WT_B, ws + OFF_BS_B, ws + OFF_GB, nullptr, nullptr, 32768, 512, 64, 64);
  // 6. LSTM recurrence (fwd + bwd concurrently), writes Hcat over X2
  lstm_k<<<dim3(32,2), dim3(512), 0, stream>>>(ws + OFF_GF, ws + OFF_GB, Whh_f, Whh_b, ws + OFF_X2);
  // 7. conv2 as im2col GEMM (K = 5*256), bias+relu
  gemm_tpl<128,128,2,2,true><<<dim3(256,1), b256, 0, stream>>>(
      ws + OFF_X2, ws + OFF_W2R, conv2_b, ws + OFF_F2, nullptr, nullptr, 32768, 128, 1280, 256);
  // 8. emissions + repeat to 101 states
  emis_k<<<dim3(8192), b256, 0, stream>>>(ws + OFF_F2, W_emis, b_emis, ws + OFF_EMIS);
  // 9. CRF pass 1: forward (blocks 0-31) + Viterbi+backtrace (blocks 32-63), concurrent
  crf1_k<<<dim3(64), dim3(64), 0, stream>>>(ws + OFF_EMIS, crf_trans, crf_start, crf_end,
                                            ws + OFF_ALPHA, ws + OFF_LOGZ,
                                            out + 3309568, ws + OFF_VBEST);
  // 10. CRF pass 2: backward, unnormalized alpha+beta into probs area
  crf_bwd_k<<<dim3(32), dim3(64), 0, stream>>>(ws + OFF_EMIS, ws + OFF_ALPHA,
                                               crf_trans, crf_end, out);
  // 11. CRF pass 3: row softmax + path probs
  crf_norm_k<<<dim3(8192), b256, 0, stream>>>(out, ws + OFF_VBEST, ws + OFF_LOGZ,
                                              out + 3342336);
}